// Round 5
// baseline (434.038 us; speedup 1.0000x reference)
//
#include <hip/hip_runtime.h>
#include <stdint.h>

#define B_ 4
#define N_ 2048
#define H_ 16
#define D_ 64
#define QD 1024
#define SCALE 0.125f
#define LOG2E 1.44269504f

typedef __bf16 bf16x8 __attribute__((ext_vector_type(8)));
typedef float f32x4 __attribute__((ext_vector_type(4)));
typedef float f32x16 __attribute__((ext_vector_type(16)));
typedef unsigned short u16x8 __attribute__((ext_vector_type(8)));
typedef unsigned short ushort_t;

__device__ __forceinline__ unsigned short f2bf(float f) {
  union { float f; unsigned u; } x; x.f = f;
  unsigned r = (x.u + 0x7fffu + ((x.u >> 16) & 1u)) >> 16;
  return (unsigned short)r;
}

__device__ __forceinline__ void ldg2lds16(const void* g, void* l) {
  __builtin_amdgcn_global_load_lds(
      (const __attribute__((address_space(1))) void*)g,
      (__attribute__((address_space(3))) void*)l, 16, 0, 0);
}

__device__ __forceinline__ ushort_t bfbits(float f) {
  union { __bf16 b; ushort_t u; } x; x.b = (__bf16)f; return x.u;
}

// ---------------- x fp32 -> bf16 ----------------
__global__ __launch_bounds__(256) void k_cvt_bf16(const float* __restrict__ in,
                                                  ushort_t* __restrict__ out, int n8) {
  int i = blockIdx.x * 256 + threadIdx.x;
  if (i >= n8) return;
  const float4* p = (const float4*)in + (size_t)i * 2;
  float4 a = p[0], b = p[1];
  u16x8 r;
  r[0] = f2bf(a.x); r[1] = f2bf(a.y); r[2] = f2bf(a.z); r[3] = f2bf(a.w);
  r[4] = f2bf(b.x); r[5] = f2bf(b.y); r[6] = f2bf(b.z); r[7] = f2bf(b.w);
  *((u16x8*)out + i) = r;
}

// ---------------- Wq,Wo transpose + convert: WT[n][k] = (bf16)W[k][n] ----------------
__global__ __launch_bounds__(256) void k_transpose_w(const float* __restrict__ Wq,
    const float* __restrict__ Wo, ushort_t* __restrict__ WqT, ushort_t* __restrict__ WoT) {
  const float* W = blockIdx.z ? Wo : Wq;
  ushort_t* WT = blockIdx.z ? WoT : WqT;
  __shared__ float tile[64][65];
  int n0 = blockIdx.x * 64, k0 = blockIdx.y * 64;
  int tx = threadIdx.x & 63, ty = threadIdx.x >> 6;
#pragma unroll
  for (int i = 0; i < 64; i += 4)
    tile[ty + i][tx] = W[(size_t)(k0 + ty + i) * QD + n0 + tx];
  __syncthreads();
#pragma unroll
  for (int i = 0; i < 64; i += 4)
    WT[(size_t)(n0 + ty + i) * QD + k0 + tx] = f2bf(tile[tx][ty + i]);
}

// ---------------- q [b][n][h*64+d] -> qT [bh][d][n] (bf16) ----------------
__global__ __launch_bounds__(256) void k_transpose_q(const ushort_t* __restrict__ qb,
                                                     ushort_t* __restrict__ qT) {
  const int bh = blockIdx.y, b = bh >> 4, h = bh & 15;
  const int n0 = blockIdx.x * 64;
  const int t = threadIdx.x;
  __shared__ ushort_t tile[64][72];
  const ushort_t* src = qb + ((size_t)b * N_ + n0) * QD + h * D_;
#pragma unroll
  for (int p = 0; p < 2; p++) {
    int r = (t >> 3) + p * 32;
    u16x8 v = *(const u16x8*)&src[(size_t)r * QD + (t & 7) * 8];
    *(u16x8*)&tile[r][(t & 7) * 8] = v;
  }
  __syncthreads();
  ushort_t* dst = qT + (size_t)bh * D_ * N_ + n0;
#pragma unroll
  for (int p = 0; p < 2; p++) {
    int d = (t >> 3) + p * 32;
    union { ushort_t s[8]; u16x8 v; } o;
#pragma unroll
    for (int e = 0; e < 8; e++) o.s[e] = tile[(t & 7) * 8 + e][d];
    *(u16x8*)&dst[(size_t)d * N_ + (t & 7) * 8] = o.v;
  }
}

// ---------------- ctx projections ----------------
__global__ __launch_bounds__(256) void k_ctx_partial(const float* __restrict__ ctx,
    const float* __restrict__ Wk, const float* __restrict__ Wv, float* __restrict__ part) {
  int ich = blockIdx.x;
  int ks = blockIdx.y;
  int kv = blockIdx.z;
  const float* W = kv ? Wv : Wk;
  __shared__ float cs[B_][128];
  int t = threadIdx.x;
  for (int i = t; i < B_ * 128; i += 256)
    cs[i >> 7][i & 127] = ctx[(size_t)(i >> 7) * QD + ks * 128 + (i & 127)];
  __syncthreads();
  int col = ich * 256 + t;
  float a0 = 0, a1 = 0, a2 = 0, a3 = 0;
  for (int k = 0; k < 128; k++) {
    float w = W[(size_t)(ks * 128 + k) * QD + col];
    a0 += cs[0][k] * w; a1 += cs[1][k] * w; a2 += cs[2][k] * w; a3 += cs[3][k] * w;
  }
  float* p = part + (size_t)(ks * 2 + kv) * (B_ * QD);
  p[0 * QD + col] = a0; p[1 * QD + col] = a1; p[2 * QD + col] = a2; p[3 * QD + col] = a3;
}

__global__ __launch_bounds__(256) void k_ctx_reduce(const float* __restrict__ part,
    float* __restrict__ kctx, float* __restrict__ vctx) {
  int idx = blockIdx.x * 256 + threadIdx.x;
  int kv = idx >> 12;
  int rest = idx & 4095;
  float acc = 0;
  for (int ks = 0; ks < 8; ks++) acc += part[(size_t)(ks * 2 + kv) * 4096 + rest];
  (kv ? vctx : kctx)[rest] = acc;
}

// ---------------- bf16 GEMM: C[M][1024] = A[M][1024] @ B^T ----------------
template <int BF16OUT>
__global__ __launch_bounds__(256) void k_gemm(const ushort_t* __restrict__ A,
    const ushort_t* __restrict__ Bm, ushort_t* __restrict__ Cb, float* __restrict__ Cf,
    const float* __restrict__ bias) {
  __shared__ ushort_t As[128 * 32];
  __shared__ ushort_t Bs[128 * 32];
  const int t = threadIdx.x;
  const int w = t >> 6, l = t & 63;
  const int wr = w >> 1, wc = w & 1;
  const int lr = l & 15, lg = l >> 4;
  const int m0 = blockIdx.y * 128, n0 = blockIdx.x * 128;
  f32x4 acc[4][4] = {};
  for (int k0 = 0; k0 < QD; k0 += 32) {
    ldg2lds16(&A[(size_t)(m0 + (t >> 2)) * QD + k0 + (t & 3) * 8], &As[t * 8]);
    ldg2lds16(&A[(size_t)(m0 + ((t + 256) >> 2)) * QD + k0 + (t & 3) * 8], &As[(t + 256) * 8]);
    ldg2lds16(&Bm[(size_t)(n0 + (t >> 2)) * QD + k0 + (t & 3) * 8], &Bs[t * 8]);
    ldg2lds16(&Bm[(size_t)(n0 + ((t + 256) >> 2)) * QD + k0 + (t & 3) * 8], &Bs[(t + 256) * 8]);
    __syncthreads();
    bf16x8 af[4], bfr[4];
#pragma unroll
    for (int m = 0; m < 4; m++)
      af[m] = *(const bf16x8*)&As[(wr * 64 + m * 16 + lr) * 32 + lg * 8];
#pragma unroll
    for (int n = 0; n < 4; n++)
      bfr[n] = *(const bf16x8*)&Bs[(wc * 64 + n * 16 + lr) * 32 + lg * 8];
#pragma unroll
    for (int m = 0; m < 4; m++)
#pragma unroll
      for (int n = 0; n < 4; n++)
        acc[m][n] = __builtin_amdgcn_mfma_f32_16x16x32_bf16(af[m], bfr[n], acc[m][n], 0, 0, 0);
    __syncthreads();
  }
#pragma unroll
  for (int m = 0; m < 4; m++) {
    int row = m0 + wr * 64 + m * 16 + lg * 4;
#pragma unroll
    for (int n = 0; n < 4; n++) {
      int col = n0 + wc * 64 + n * 16 + lr;
#pragma unroll
      for (int j = 0; j < 4; j++) {
        float v = acc[m][n][j];
        if constexpr (BF16OUT) {
          Cb[(size_t)(row + j) * QD + col] = f2bf(v);
        } else {
          Cf[(size_t)(row + j) * QD + col] = v + bias[col];
        }
      }
    }
  }
}

// ---------------- flash attention v4: no LDS, no barriers ----------------
// K/V working set per (b,h) is 256 KB -> L2-resident; each wave reads K
// fragments directly from q and V^T fragments directly from qT. One wave per
// block (64 thr), 32 q-rows per wave, independent causal walk. Softmax in
// exp2 space. Fragment mappings identical to the verified k_attn3.
__global__ __launch_bounds__(64) void k_attn4(
    const ushort_t* __restrict__ q, const ushort_t* __restrict__ qT,
    const float* __restrict__ kctx, const float* __restrict__ vctx,
    ushort_t* __restrict__ att) {
  const int xb = blockIdx.x;
  const int qt = (xb & 1) ? (63 - (xb >> 1)) : (xb >> 1);  // heavy/light pairing
  const int bh = blockIdx.y;
  const int b = bh >> 4, h = bh & 15;
  const int l = threadIdx.x & 63;
  const int lq = l & 31, hi = l >> 5;
  const int wq0 = qt * 32;

  const ushort_t* qbase = q + (size_t)b * N_ * QD + h * D_;
  const ushort_t* qtb = qT + (size_t)bh * D_ * N_;

  // Q fragments (B-operand of S^T = K*Q^T): row wq0+lq, k = kk*16 + hi*8 + j
  bf16x8 qf[4];
#pragma unroll
  for (int kk = 0; kk < 4; kk++)
    qf[kk] = *(const bf16x8*)&qbase[(size_t)(wq0 + lq) * QD + kk * 16 + hi * 8];

  // ctx token = softmax initializer: m2 = logit_ctx (log2 space), l = 1, O = v_ctx
  const float* kc = kctx + bh * D_;
  const float* vc = vctx + bh * D_;
  float m2, lsum;
  f32x16 oacc[2];
  {
    float dot = 0.f;
#pragma unroll
    for (int kk = 0; kk < 4; kk++)
#pragma unroll
      for (int j = 0; j < 8; j++)
        dot += (float)qf[kk][j] * kc[kk * 16 + hi * 8 + j];
    dot += __shfl_xor(dot, 32);
    m2 = dot * (SCALE * LOG2E);
    lsum = 1.0f;
#pragma unroll
    for (int dt = 0; dt < 2; dt++)
#pragma unroll
      for (int r = 0; r < 16; r++)
        oacc[dt][r] = vc[dt * 32 + (r & 3) + 8 * (r >> 2) + 4 * hi];
  }

  const int NT = qt / 2 + 1;
  for (int tt = 0; tt < NT; ++tt) {
    const int j0 = tt * 64;
    const ushort_t* kb0 = qbase + (size_t)j0 * QD;

    // ---- S^T = K * Q^T : p[kb] (rows = keys, cols = q) ----
    f32x16 p[2];
#pragma unroll
    for (int kb = 0; kb < 2; kb++) {
      f32x16 acc;
#pragma unroll
      for (int r = 0; r < 16; r++) acc[r] = 0.f;
#pragma unroll
      for (int kk = 0; kk < 4; kk++) {
        bf16x8 kf = *(const bf16x8*)&kb0[(size_t)(kb * 32 + lq) * QD + kk * 16 + hi * 8];
        acc = __builtin_amdgcn_mfma_f32_32x32x16_bf16(kf, qf[kk], acc, 0, 0, 0);
      }
      p[kb] = acc;
    }

    // ---- causal mask (only the diagonal tile) ----
    if (j0 + 63 > wq0) {
      const int qrel = wq0 - j0 + lq;
#pragma unroll
      for (int kb = 0; kb < 2; kb++)
#pragma unroll
        for (int r = 0; r < 16; r++) {
          int key = kb * 32 + (r & 3) + 8 * (r >> 2) + 4 * hi;
          if (key > qrel) p[kb][r] = -1e30f;
        }
    }

    // ---- online softmax (lane-local rows, exp2 space) ----
    float rm = p[0][0];
#pragma unroll
    for (int r = 1; r < 16; r++) rm = fmaxf(rm, p[0][r]);
#pragma unroll
    for (int r = 0; r < 16; r++) rm = fmaxf(rm, p[1][r]);
    rm = fmaxf(rm, __shfl_xor(rm, 32));
    const float m2n = fmaxf(m2, rm * (SCALE * LOG2E));
    const float corr = __builtin_exp2f(m2 - m2n);
    m2 = m2n;
    float rs = 0.f;
#pragma unroll
    for (int kb = 0; kb < 2; kb++)
#pragma unroll
      for (int r = 0; r < 16; r++) {
        float e = __builtin_exp2f(fmaf(p[kb][r], (SCALE * LOG2E), -m2n));
        p[kb][r] = e;
        rs += e;
      }
    rs += __shfl_xor(rs, 32);
    lsum = lsum * corr + rs;
#pragma unroll
    for (int dt = 0; dt < 2; dt++)
#pragma unroll
      for (int r = 0; r < 16; r++) oacc[dt][r] *= corr;

    // ---- P -> bf16 B-fragments (pack pairs + half-swap), then PV ----
#pragma unroll
    for (int kb = 0; kb < 2; kb++) {
      unsigned u[8], sw[8];
#pragma unroll
      for (int i = 0; i < 8; i++) {
        union { __bf16 b2[2]; unsigned v; } pk2;
        pk2.b2[0] = (__bf16)p[kb][2 * i];
        pk2.b2[1] = (__bf16)p[kb][2 * i + 1];
        u[i] = pk2.v;
      }
#pragma unroll
      for (int i = 0; i < 8; i++) sw[i] = (unsigned)__shfl_xor((int)u[i], 32);
      union { unsigned u4[4]; bf16x8 v; } pf0, pf1;
      pf0.u4[0] = hi ? sw[2] : u[0]; pf0.u4[1] = hi ? sw[3] : u[1];
      pf0.u4[2] = hi ? u[2] : sw[0]; pf0.u4[3] = hi ? u[3] : sw[1];
      pf1.u4[0] = hi ? sw[6] : u[4]; pf1.u4[1] = hi ? sw[7] : u[5];
      pf1.u4[2] = hi ? u[6] : sw[4]; pf1.u4[3] = hi ? u[7] : sw[5];
#pragma unroll
      for (int ks = 0; ks < 2; ks++) {
        const bf16x8 pf = ks ? pf1.v : pf0.v;
#pragma unroll
        for (int dt = 0; dt < 2; dt++) {
          bf16x8 vf = *(const bf16x8*)&qtb[(size_t)(dt * 32 + lq) * N_ +
                                           j0 + kb * 32 + ks * 16 + hi * 8];
          oacc[dt] = __builtin_amdgcn_mfma_f32_32x32x16_bf16(vf, pf, oacc[dt], 0, 0, 0);
        }
      }
    }
  }

  // ---- epilogue: O^T regs -> att (bf16) ----
  const float inv = 1.0f / lsum;
  ushort_t* ob = att + (size_t)b * N_ * QD + (size_t)(wq0 + lq) * QD + h * D_;
#pragma unroll
  for (int dt = 0; dt < 2; dt++)
#pragma unroll
    for (int rq = 0; rq < 4; rq++) {
      union { ushort_t s4[4]; unsigned long long v; } o;
#pragma unroll
      for (int e = 0; e < 4; e++) o.s4[e] = bfbits(oacc[dt][rq * 4 + e] * inv);
      *(unsigned long long*)(ob + dt * 32 + 8 * rq + 4 * hi) = o.v;
    }
}

extern "C" void kernel_launch(void* const* d_in, const int* in_sizes, int n_in,
                              void* d_out, int out_size, void* d_ws, size_t ws_size,
                              hipStream_t stream) {
  const float* x = (const float*)d_in[0];
  const float* ctx = (const float*)d_in[1];
  const float* Wq = (const float*)d_in[2];
  const float* Wk = (const float*)d_in[3];
  const float* Wv = (const float*)d_in[4];
  const float* Wo = (const float*)d_in[5];
  const float* bo = (const float*)d_in[6];
  float* out = (float*)d_out;

  char* ws = (char*)d_ws;
  size_t off = 0;
  ushort_t* xb = (ushort_t*)(ws + off);   off += (size_t)8192 * 1024 * 2;  // reused as qT
  ushort_t* qb = (ushort_t*)(ws + off);   off += (size_t)8192 * 1024 * 2;
  ushort_t* attb = (ushort_t*)(ws + off); off += (size_t)8192 * 1024 * 2;
  ushort_t* WqT = (ushort_t*)(ws + off);  off += (size_t)1024 * 1024 * 2;
  ushort_t* WoT = (ushort_t*)(ws + off);  off += (size_t)1024 * 1024 * 2;
  float* kctx = (float*)(ws + off);       off += (size_t)4096 * 4;
  float* vctx = (float*)(ws + off);       off += (size_t)4096 * 4;
  float* part = (float*)(ws + off);       off += (size_t)16 * 4096 * 4;
  ushort_t* qT = xb;  // xb is dead after k_gemm<1>

  k_cvt_bf16<<<dim3(4096), dim3(256), 0, stream>>>(x, xb, 8192 * 1024 / 8);
  k_transpose_w<<<dim3(16, 16, 2), dim3(256), 0, stream>>>(Wq, Wo, WqT, WoT);
  k_ctx_partial<<<dim3(4, 8, 2), dim3(256), 0, stream>>>(ctx, Wk, Wv, part);
  k_ctx_reduce<<<dim3(32), dim3(256), 0, stream>>>(part, kctx, vctx);
  k_gemm<1><<<dim3(8, 64), dim3(256), 0, stream>>>(xb, WqT, qb, nullptr, nullptr);
  k_transpose_q<<<dim3(32, 64), dim3(256), 0, stream>>>(qb, qT);
  k_attn4<<<dim3(128, 64), dim3(64), 0, stream>>>(qb, qT, kctx, vctx, attb);
  k_gemm<0><<<dim3(8, 64), dim3(256), 0, stream>>>(attb, WoT, nullptr, out, bo);
}

// Round 6
// 185.706 us; speedup vs baseline: 2.3372x; 2.3372x over previous
//
#include <hip/hip_runtime.h>
#include <stdint.h>

#define B_ 4
#define N_ 2048
#define H_ 16
#define D_ 64
#define QD 1024
#define SCALE 0.125f
#define LOG2E 1.44269504f
#define SC2 (SCALE * LOG2E)

typedef __bf16 bf16x8 __attribute__((ext_vector_type(8)));
typedef float f32x4 __attribute__((ext_vector_type(4)));
typedef float f32x16 __attribute__((ext_vector_type(16)));
typedef unsigned short u16x8 __attribute__((ext_vector_type(8)));
typedef unsigned short ushort_t;

__device__ __forceinline__ unsigned short f2bf(float f) {
  union { float f; unsigned u; } x; x.f = f;
  unsigned r = (x.u + 0x7fffu + ((x.u >> 16) & 1u)) >> 16;
  return (unsigned short)r;
}

__device__ __forceinline__ void ldg2lds16(const void* g, void* l) {
  __builtin_amdgcn_global_load_lds(
      (const __attribute__((address_space(1))) void*)g,
      (__attribute__((address_space(3))) void*)l, 16, 0, 0);
}

__device__ __forceinline__ ushort_t bfbits(float f) {
  union { __bf16 b; ushort_t u; } x; x.b = (__bf16)f; return x.u;
}

// ---------------- x fp32 -> bf16 ----------------
__global__ __launch_bounds__(256) void k_cvt_bf16(const float* __restrict__ in,
                                                  ushort_t* __restrict__ out, int n8) {
  int i = blockIdx.x * 256 + threadIdx.x;
  if (i >= n8) return;
  const float4* p = (const float4*)in + (size_t)i * 2;
  float4 a = p[0], b = p[1];
  u16x8 r;
  r[0] = f2bf(a.x); r[1] = f2bf(a.y); r[2] = f2bf(a.z); r[3] = f2bf(a.w);
  r[4] = f2bf(b.x); r[5] = f2bf(b.y); r[6] = f2bf(b.z); r[7] = f2bf(b.w);
  *((u16x8*)out + i) = r;
}

// ---------------- Wq,Wo transpose + convert: WT[n][k] = (bf16)W[k][n] ----------------
__global__ __launch_bounds__(256) void k_transpose_w(const float* __restrict__ Wq,
    const float* __restrict__ Wo, ushort_t* __restrict__ WqT, ushort_t* __restrict__ WoT) {
  const float* W = blockIdx.z ? Wo : Wq;
  ushort_t* WT = blockIdx.z ? WoT : WqT;
  __shared__ float tile[64][65];
  int n0 = blockIdx.x * 64, k0 = blockIdx.y * 64;
  int tx = threadIdx.x & 63, ty = threadIdx.x >> 6;
#pragma unroll
  for (int i = 0; i < 64; i += 4)
    tile[ty + i][tx] = W[(size_t)(k0 + ty + i) * QD + n0 + tx];
  __syncthreads();
#pragma unroll
  for (int i = 0; i < 64; i += 4)
    WT[(size_t)(n0 + ty + i) * QD + k0 + tx] = f2bf(tile[tx][ty + i]);
}

// ---------------- q [b][n][h*64+d] -> qT [bh][d][n] (bf16) ----------------
__global__ __launch_bounds__(256) void k_transpose_q(const ushort_t* __restrict__ qb,
                                                     ushort_t* __restrict__ qT) {
  const int bh = blockIdx.y, b = bh >> 4, h = bh & 15;
  const int n0 = blockIdx.x * 64;
  const int t = threadIdx.x;
  __shared__ ushort_t tile[64][72];
  const ushort_t* src = qb + ((size_t)b * N_ + n0) * QD + h * D_;
#pragma unroll
  for (int p = 0; p < 2; p++) {
    int r = (t >> 3) + p * 32;
    u16x8 v = *(const u16x8*)&src[(size_t)r * QD + (t & 7) * 8];
    *(u16x8*)&tile[r][(t & 7) * 8] = v;
  }
  __syncthreads();
  ushort_t* dst = qT + (size_t)bh * D_ * N_ + n0;
#pragma unroll
  for (int p = 0; p < 2; p++) {
    int d = (t >> 3) + p * 32;
    union { ushort_t s[8]; u16x8 v; } o;
#pragma unroll
    for (int e = 0; e < 8; e++) o.s[e] = tile[(t & 7) * 8 + e][d];
    *(u16x8*)&dst[(size_t)d * N_ + (t & 7) * 8] = o.v;
  }
}

// ---------------- ctx projections ----------------
__global__ __launch_bounds__(256) void k_ctx_partial(const float* __restrict__ ctx,
    const float* __restrict__ Wk, const float* __restrict__ Wv, float* __restrict__ part) {
  int ich = blockIdx.x;
  int ks = blockIdx.y;
  int kv = blockIdx.z;
  const float* W = kv ? Wv : Wk;
  __shared__ float cs[B_][128];
  int t = threadIdx.x;
  for (int i = t; i < B_ * 128; i += 256)
    cs[i >> 7][i & 127] = ctx[(size_t)(i >> 7) * QD + ks * 128 + (i & 127)];
  __syncthreads();
  int col = ich * 256 + t;
  float a0 = 0, a1 = 0, a2 = 0, a3 = 0;
  for (int k = 0; k < 128; k++) {
    float w = W[(size_t)(ks * 128 + k) * QD + col];
    a0 += cs[0][k] * w; a1 += cs[1][k] * w; a2 += cs[2][k] * w; a3 += cs[3][k] * w;
  }
  float* p = part + (size_t)(ks * 2 + kv) * (B_ * QD);
  p[0 * QD + col] = a0; p[1 * QD + col] = a1; p[2 * QD + col] = a2; p[3 * QD + col] = a3;
}

__global__ __launch_bounds__(256) void k_ctx_reduce(const float* __restrict__ part,
    float* __restrict__ kctx, float* __restrict__ vctx) {
  int idx = blockIdx.x * 256 + threadIdx.x;
  int kv = idx >> 12;
  int rest = idx & 4095;
  float acc = 0;
  for (int ks = 0; ks < 8; ks++) acc += part[(size_t)(ks * 2 + kv) * 4096 + rest];
  (kv ? vctx : kctx)[rest] = acc;
}

// ---------------- bf16 GEMM: C[M][1024] = A[M][1024] @ B^T ----------------
template <int BF16OUT>
__global__ __launch_bounds__(256) void k_gemm(const ushort_t* __restrict__ A,
    const ushort_t* __restrict__ Bm, ushort_t* __restrict__ Cb, float* __restrict__ Cf,
    const float* __restrict__ bias) {
  __shared__ ushort_t As[128 * 32];
  __shared__ ushort_t Bs[128 * 32];
  const int t = threadIdx.x;
  const int w = t >> 6, l = t & 63;
  const int wr = w >> 1, wc = w & 1;
  const int lr = l & 15, lg = l >> 4;
  const int m0 = blockIdx.y * 128, n0 = blockIdx.x * 128;
  f32x4 acc[4][4] = {};
  for (int k0 = 0; k0 < QD; k0 += 32) {
    ldg2lds16(&A[(size_t)(m0 + (t >> 2)) * QD + k0 + (t & 3) * 8], &As[t * 8]);
    ldg2lds16(&A[(size_t)(m0 + ((t + 256) >> 2)) * QD + k0 + (t & 3) * 8], &As[(t + 256) * 8]);
    ldg2lds16(&Bm[(size_t)(n0 + (t >> 2)) * QD + k0 + (t & 3) * 8], &Bs[t * 8]);
    ldg2lds16(&Bm[(size_t)(n0 + ((t + 256) >> 2)) * QD + k0 + (t & 3) * 8], &Bs[(t + 256) * 8]);
    __syncthreads();
    bf16x8 af[4], bfr[4];
#pragma unroll
    for (int m = 0; m < 4; m++)
      af[m] = *(const bf16x8*)&As[(wr * 64 + m * 16 + lr) * 32 + lg * 8];
#pragma unroll
    for (int n = 0; n < 4; n++)
      bfr[n] = *(const bf16x8*)&Bs[(wc * 64 + n * 16 + lr) * 32 + lg * 8];
#pragma unroll
    for (int m = 0; m < 4; m++)
#pragma unroll
      for (int n = 0; n < 4; n++)
        acc[m][n] = __builtin_amdgcn_mfma_f32_16x16x32_bf16(af[m], bfr[n], acc[m][n], 0, 0, 0);
    __syncthreads();
  }
#pragma unroll
  for (int m = 0; m < 4; m++) {
    int row = m0 + wr * 64 + m * 16 + lg * 4;
#pragma unroll
    for (int n = 0; n < 4; n++) {
      int col = n0 + wc * 64 + n * 16 + lr;
#pragma unroll
      for (int j = 0; j < 4; j++) {
        float v = acc[m][n][j];
        if constexpr (BF16OUT) {
          Cb[(size_t)(row + j) * QD + col] = f2bf(v);
        } else {
          Cf[(size_t)(row + j) * QD + col] = v + bias[col];
        }
      }
    }
  }
}

// ---------------- flash attention v5: attn3 + per-CU work balance + defer-rescale ----
// Same verified structure/layouts as attn3 (R4, passing). Changes:
//  * qt chosen so the 4 co-resident blocks per CU (ids differ by 256 ->
//    y>>4 = 0..3) get qt sets {x, 15-x, (x+8)&15, (7-x)&15}: per-CU tile
//    work = 68 units for EVERY CU (was up to 128).
//  * softmax in exp2 space; defer-rescale (skip O*corr when max grew <= 8).
__global__ __launch_bounds__(256, 2) void k_attn3(
    const ushort_t* __restrict__ q, const ushort_t* __restrict__ qT,
    const float* __restrict__ kctx, const float* __restrict__ vctx,
    ushort_t* __restrict__ att) {
  const int x = blockIdx.x;        // 0..15
  const int bh = blockIdx.y;       // 0..63
  const int g = bh >> 4;           // 0..3 : varies across a CU's resident blocks
  const int xx = (g & 2) ? ((x + 8) & 15) : x;
  const int qt = (g & 1) ? (15 - xx) : xx;   // bijective per bh; per-CU sum balanced
  const int b = bh >> 4, h = bh & 15;
  const int t = threadIdx.x, w = t >> 6, l = t & 63;
  const int lq = l & 31, hi = l >> 5;
  const int i0 = qt * 128;
  const int wq0 = i0 + w * 32;

  __shared__ __align__(128) ushort_t Ks[2][4096];
  __shared__ __align__(128) ushort_t Vs[2][4096];

  const ushort_t* qbase = q + (size_t)b * N_ * QD + h * D_;
  const ushort_t* qtb = qT + (size_t)bh * D_ * N_;

  // Q fragments (B-operand of S^T = K*Q^T): row wq0+lq, k = kk*16 + hi*8 + j
  bf16x8 qf[4];
#pragma unroll
  for (int kk = 0; kk < 4; kk++)
    qf[kk] = *(const bf16x8*)&qbase[(size_t)(wq0 + lq) * QD + kk * 16 + hi * 8];

  // ctx token = softmax initializer: m2 = logit_ctx (log2 space), l = 1, O = v_ctx
  const float* kc = kctx + bh * D_;
  const float* vc = vctx + bh * D_;
  float m2, lsum;
  f32x16 oacc[2];
  {
    float dot = 0.f;
#pragma unroll
    for (int kk = 0; kk < 4; kk++)
#pragma unroll
      for (int j = 0; j < 8; j++)
        dot += (float)qf[kk][j] * kc[kk * 16 + hi * 8 + j];
    dot += __shfl_xor(dot, 32);
    m2 = dot * SC2;
    lsum = 1.0f;
#pragma unroll
    for (int dt = 0; dt < 2; dt++)
#pragma unroll
      for (int r = 0; r < 16; r++)
        oacc[dt][r] = vc[dt * 32 + (r & 3) + 8 * (r >> 2) + 4 * hi];
  }

  const int NT = 2 * qt + 2;

  // ---- stage tile 0 ----
  {
    const int j0 = 0;
#pragma unroll
    for (int rep = 0; rep < 2; rep++) {
      int c = t + rep * 256;
      int row = c >> 3, c0 = 8 * ((c & 7) ^ ((c >> 3) & 7));
      ldg2lds16(&qbase[(size_t)(j0 + row) * QD + c0], &Ks[0][c * 8]);
      ldg2lds16(&qtb[(size_t)row * N_ + j0 + c0], &Vs[0][c * 8]);
    }
  }

  for (int tt = 0; tt < NT; ++tt) {
    const int cur = tt & 1;
    if (tt + 1 < NT) {
      const int j1 = (tt + 1) * 64;
#pragma unroll
      for (int rep = 0; rep < 2; rep++) {
        int c = t + rep * 256;
        int row = c >> 3, c0 = 8 * ((c & 7) ^ ((c >> 3) & 7));
        ldg2lds16(&qbase[(size_t)(j1 + row) * QD + c0], &Ks[cur ^ 1][c * 8]);
        ldg2lds16(&qtb[(size_t)row * N_ + j1 + c0], &Vs[cur ^ 1][c * 8]);
      }
      asm volatile("s_waitcnt vmcnt(4)" ::: "memory");
    } else {
      asm volatile("s_waitcnt vmcnt(0)" ::: "memory");
    }
    __builtin_amdgcn_s_barrier();

    const int j0 = tt * 64;
    if (j0 <= wq0 + 31) {  // wave-level causal skip
      const char* ksb = (const char*)&Ks[cur][0];
      const char* vsb = (const char*)&Vs[cur][0];

      // ---- S^T = K * Q^T : p[kb] (rows = keys, cols = q) ----
      f32x16 p[2];
#pragma unroll
      for (int kb = 0; kb < 2; kb++) {
        f32x16 acc;
#pragma unroll
        for (int r = 0; r < 16; r++) acc[r] = 0.f;
#pragma unroll
        for (int kk = 0; kk < 4; kk++) {
          bf16x8 kf = *(const bf16x8*)(ksb + (l & 31) * 128 + kb * 4096 +
                                       (((kk * 2 + hi) ^ (l & 7)) << 4));
          acc = __builtin_amdgcn_mfma_f32_32x32x16_bf16(kf, qf[kk], acc, 0, 0, 0);
        }
        p[kb] = acc;
      }

      // ---- causal mask (only near the diagonal) ----
      if (j0 + 63 > wq0) {
        const int qrel = wq0 - j0 + lq;
#pragma unroll
        for (int kb = 0; kb < 2; kb++)
#pragma unroll
          for (int r = 0; r < 16; r++) {
            int key = kb * 32 + (r & 3) + 8 * (r >> 2) + 4 * hi;
            if (key > qrel) p[kb][r] = -1e30f;
          }
      }

      // ---- online softmax (lane-local rows, exp2 space, defer-rescale) ----
      float rm = p[0][0];
#pragma unroll
      for (int r = 1; r < 16; r++) rm = fmaxf(rm, p[0][r]);
#pragma unroll
      for (int r = 0; r < 16; r++) rm = fmaxf(rm, p[1][r]);
      rm = fmaxf(rm, __shfl_xor(rm, 32));
      const float rmS = rm * SC2;
      if (!__all(rmS <= m2 + 8.0f)) {
        const float m2n = fmaxf(m2, rmS);
        const float corr = __builtin_exp2f(m2 - m2n);
        m2 = m2n;
        lsum *= corr;
#pragma unroll
        for (int dt = 0; dt < 2; dt++)
#pragma unroll
          for (int r = 0; r < 16; r++) oacc[dt][r] *= corr;
      }
      float rs = 0.f;
#pragma unroll
      for (int kb = 0; kb < 2; kb++)
#pragma unroll
        for (int r = 0; r < 16; r++) {
          float e = __builtin_exp2f(fmaf(p[kb][r], SC2, -m2));
          p[kb][r] = e;
          rs += e;
        }
      rs += __shfl_xor(rs, 32);
      lsum += rs;

      // ---- P -> bf16 B-fragments (pack pairs + half-swap), then PV ----
#pragma unroll
      for (int kb = 0; kb < 2; kb++) {
        unsigned u[8], sw[8];
#pragma unroll
        for (int i = 0; i < 8; i++) {
          union { __bf16 b2[2]; unsigned v; } pk2;
          pk2.b2[0] = (__bf16)p[kb][2 * i];
          pk2.b2[1] = (__bf16)p[kb][2 * i + 1];
          u[i] = pk2.v;
        }
#pragma unroll
        for (int i = 0; i < 8; i++) sw[i] = (unsigned)__shfl_xor((int)u[i], 32);
        union { unsigned u4[4]; bf16x8 v; } pf0, pf1;
        pf0.u4[0] = hi ? sw[2] : u[0]; pf0.u4[1] = hi ? sw[3] : u[1];
        pf0.u4[2] = hi ? u[2] : sw[0]; pf0.u4[3] = hi ? u[3] : sw[1];
        pf1.u4[0] = hi ? sw[6] : u[4]; pf1.u4[1] = hi ? sw[7] : u[5];
        pf1.u4[2] = hi ? u[6] : sw[4]; pf1.u4[3] = hi ? u[7] : sw[5];
#pragma unroll
        for (int ks = 0; ks < 2; ks++) {
          const bf16x8 pf = ks ? pf1.v : pf0.v;
#pragma unroll
          for (int dt = 0; dt < 2; dt++) {
            bf16x8 vf = *(const bf16x8*)(vsb + (l & 31) * 128 + dt * 4096 +
                                         (((kb * 4 + ks * 2 + hi) ^ (l & 7)) << 4));
            oacc[dt] = __builtin_amdgcn_mfma_f32_32x32x16_bf16(vf, pf, oacc[dt], 0, 0, 0);
          }
        }
      }
    }
    __builtin_amdgcn_s_barrier();
  }

  // ---- epilogue: O^T regs -> att (bf16) ----
  const float inv = 1.0f / lsum;
  ushort_t* ob = att + (size_t)b * N_ * QD + (size_t)(wq0 + lq) * QD + h * D_;
#pragma unroll
  for (int dt = 0; dt < 2; dt++)
#pragma unroll
    for (int rq = 0; rq < 4; rq++) {
      union { ushort_t s4[4]; unsigned long long v; } o;
#pragma unroll
      for (int e = 0; e < 4; e++) o.s4[e] = bfbits(oacc[dt][rq * 4 + e] * inv);
      *(unsigned long long*)(ob + dt * 32 + 8 * rq + 4 * hi) = o.v;
    }
}

extern "C" void kernel_launch(void* const* d_in, const int* in_sizes, int n_in,
                              void* d_out, int out_size, void* d_ws, size_t ws_size,
                              hipStream_t stream) {
  const float* x = (const float*)d_in[0];
  const float* ctx = (const float*)d_in[1];
  const float* Wq = (const float*)d_in[2];
  const float* Wk = (const float*)d_in[3];
  const float* Wv = (const float*)d_in[4];
  const float* Wo = (const float*)d_in[5];
  const float* bo = (const float*)d_in[6];
  float* out = (float*)d_out;

  char* ws = (char*)d_ws;
  size_t off = 0;
  ushort_t* xb = (ushort_t*)(ws + off);   off += (size_t)8192 * 1024 * 2;  // reused as qT
  ushort_t* qb = (ushort_t*)(ws + off);   off += (size_t)8192 * 1024 * 2;
  ushort_t* attb = (ushort_t*)(ws + off); off += (size_t)8192 * 1024 * 2;
  ushort_t* WqT = (ushort_t*)(ws + off);  off += (size_t)1024 * 1024 * 2;
  ushort_t* WoT = (ushort_t*)(ws + off);  off += (size_t)1024 * 1024 * 2;
  float* kctx = (float*)(ws + off);       off += (size_t)4096 * 4;
  float* vctx = (float*)(ws + off);       off += (size_t)4096 * 4;
  float* part = (float*)(ws + off);       off += (size_t)16 * 4096 * 4;
  ushort_t* qT = xb;  // xb is dead after k_gemm<1>

  k_cvt_bf16<<<dim3(4096), dim3(256), 0, stream>>>(x, xb, 8192 * 1024 / 8);
  k_transpose_w<<<dim3(16, 16, 2), dim3(256), 0, stream>>>(Wq, Wo, WqT, WoT);
  k_ctx_partial<<<dim3(4, 8, 2), dim3(256), 0, stream>>>(ctx, Wk, Wv, part);
  k_ctx_reduce<<<dim3(32), dim3(256), 0, stream>>>(part, kctx, vctx);
  k_gemm<1><<<dim3(8, 64), dim3(256), 0, stream>>>(xb, WqT, qb, nullptr, nullptr);
  k_transpose_q<<<dim3(32, 64), dim3(256), 0, stream>>>(qb, qT);
  k_attn3<<<dim3(16, 64), dim3(256), 0, stream>>>(qb, qT, kctx, vctx, attb);
  k_gemm<0><<<dim3(8, 64), dim3(256), 0, stream>>>(attb, WoT, nullptr, out, bo);
}

// Round 7
// 179.393 us; speedup vs baseline: 2.4195x; 1.0352x over previous
//
#include <hip/hip_runtime.h>
#include <stdint.h>

#define B_ 4
#define N_ 2048
#define H_ 16
#define D_ 64
#define QD 1024
#define SCALE 0.125f
#define LOG2E 1.44269504f
#define SC2 (SCALE * LOG2E)

typedef __bf16 bf16x8 __attribute__((ext_vector_type(8)));
typedef float f32x4 __attribute__((ext_vector_type(4)));
typedef float f32x16 __attribute__((ext_vector_type(16)));
typedef unsigned short u16x8 __attribute__((ext_vector_type(8)));
typedef unsigned short ushort_t;

__device__ __forceinline__ unsigned short f2bf(float f) {
  union { float f; unsigned u; } x; x.f = f;
  unsigned r = (x.u + 0x7fffu + ((x.u >> 16) & 1u)) >> 16;
  return (unsigned short)r;
}

__device__ __forceinline__ void ldg2lds16(const void* g, void* l) {
  __builtin_amdgcn_global_load_lds(
      (const __attribute__((address_space(1))) void*)g,
      (__attribute__((address_space(3))) void*)l, 16, 0, 0);
}

__device__ __forceinline__ ushort_t bfbits(float f) {
  union { __bf16 b; ushort_t u; } x; x.b = (__bf16)f; return x.u;
}

// ---------------- x fp32 -> bf16 ----------------
__global__ __launch_bounds__(256) void k_cvt_bf16(const float* __restrict__ in,
                                                  ushort_t* __restrict__ out, int n8) {
  int i = blockIdx.x * 256 + threadIdx.x;
  if (i >= n8) return;
  const float4* p = (const float4*)in + (size_t)i * 2;
  float4 a = p[0], b = p[1];
  u16x8 r;
  r[0] = f2bf(a.x); r[1] = f2bf(a.y); r[2] = f2bf(a.z); r[3] = f2bf(a.w);
  r[4] = f2bf(b.x); r[5] = f2bf(b.y); r[6] = f2bf(b.z); r[7] = f2bf(b.w);
  *((u16x8*)out + i) = r;
}

// ---------------- Wq,Wo transpose + convert: WT[n][k] = (bf16)W[k][n] ----------------
__global__ __launch_bounds__(256) void k_transpose_w(const float* __restrict__ Wq,
    const float* __restrict__ Wo, ushort_t* __restrict__ WqT, ushort_t* __restrict__ WoT) {
  const float* W = blockIdx.z ? Wo : Wq;
  ushort_t* WT = blockIdx.z ? WoT : WqT;
  __shared__ float tile[64][65];
  int n0 = blockIdx.x * 64, k0 = blockIdx.y * 64;
  int tx = threadIdx.x & 63, ty = threadIdx.x >> 6;
#pragma unroll
  for (int i = 0; i < 64; i += 4)
    tile[ty + i][tx] = W[(size_t)(k0 + ty + i) * QD + n0 + tx];
  __syncthreads();
#pragma unroll
  for (int i = 0; i < 64; i += 4)
    WT[(size_t)(n0 + ty + i) * QD + k0 + tx] = f2bf(tile[tx][ty + i]);
}

// ---------------- q [b][n][h*64+d] -> qT [bh][d][n] (bf16) ----------------
__global__ __launch_bounds__(256) void k_transpose_q(const ushort_t* __restrict__ qb,
                                                     ushort_t* __restrict__ qT) {
  const int bh = blockIdx.y, b = bh >> 4, h = bh & 15;
  const int n0 = blockIdx.x * 64;
  const int t = threadIdx.x;
  __shared__ ushort_t tile[64][72];
  const ushort_t* src = qb + ((size_t)b * N_ + n0) * QD + h * D_;
#pragma unroll
  for (int p = 0; p < 2; p++) {
    int r = (t >> 3) + p * 32;
    u16x8 v = *(const u16x8*)&src[(size_t)r * QD + (t & 7) * 8];
    *(u16x8*)&tile[r][(t & 7) * 8] = v;
  }
  __syncthreads();
  ushort_t* dst = qT + (size_t)bh * D_ * N_ + n0;
#pragma unroll
  for (int p = 0; p < 2; p++) {
    int d = (t >> 3) + p * 32;
    union { ushort_t s[8]; u16x8 v; } o;
#pragma unroll
    for (int e = 0; e < 8; e++) o.s[e] = tile[(t & 7) * 8 + e][d];
    *(u16x8*)&dst[(size_t)d * N_ + (t & 7) * 8] = o.v;
  }
}

// ---------------- ctx projections ----------------
__global__ __launch_bounds__(256) void k_ctx_partial(const float* __restrict__ ctx,
    const float* __restrict__ Wk, const float* __restrict__ Wv, float* __restrict__ part) {
  int ich = blockIdx.x;
  int ks = blockIdx.y;
  int kv = blockIdx.z;
  const float* W = kv ? Wv : Wk;
  __shared__ float cs[B_][128];
  int t = threadIdx.x;
  for (int i = t; i < B_ * 128; i += 256)
    cs[i >> 7][i & 127] = ctx[(size_t)(i >> 7) * QD + ks * 128 + (i & 127)];
  __syncthreads();
  int col = ich * 256 + t;
  float a0 = 0, a1 = 0, a2 = 0, a3 = 0;
  for (int k = 0; k < 128; k++) {
    float w = W[(size_t)(ks * 128 + k) * QD + col];
    a0 += cs[0][k] * w; a1 += cs[1][k] * w; a2 += cs[2][k] * w; a3 += cs[3][k] * w;
  }
  float* p = part + (size_t)(ks * 2 + kv) * (B_ * QD);
  p[0 * QD + col] = a0; p[1 * QD + col] = a1; p[2 * QD + col] = a2; p[3 * QD + col] = a3;
}

__global__ __launch_bounds__(256) void k_ctx_reduce(const float* __restrict__ part,
    float* __restrict__ kctx, float* __restrict__ vctx) {
  int idx = blockIdx.x * 256 + threadIdx.x;
  int kv = idx >> 12;
  int rest = idx & 4095;
  float acc = 0;
  for (int ks = 0; ks < 8; ks++) acc += part[(size_t)(ks * 2 + kv) * 4096 + rest];
  (kv ? vctx : kctx)[rest] = acc;
}

// ---------------- bf16 GEMM: C[M][1024] = A[M][1024] @ B^T ----------------
template <int BF16OUT>
__global__ __launch_bounds__(256) void k_gemm(const ushort_t* __restrict__ A,
    const ushort_t* __restrict__ Bm, ushort_t* __restrict__ Cb, float* __restrict__ Cf,
    const float* __restrict__ bias) {
  __shared__ ushort_t As[128 * 32];
  __shared__ ushort_t Bs[128 * 32];
  const int t = threadIdx.x;
  const int w = t >> 6, l = t & 63;
  const int wr = w >> 1, wc = w & 1;
  const int lr = l & 15, lg = l >> 4;
  const int m0 = blockIdx.y * 128, n0 = blockIdx.x * 128;
  f32x4 acc[4][4] = {};
  for (int k0 = 0; k0 < QD; k0 += 32) {
    ldg2lds16(&A[(size_t)(m0 + (t >> 2)) * QD + k0 + (t & 3) * 8], &As[t * 8]);
    ldg2lds16(&A[(size_t)(m0 + ((t + 256) >> 2)) * QD + k0 + (t & 3) * 8], &As[(t + 256) * 8]);
    ldg2lds16(&Bm[(size_t)(n0 + (t >> 2)) * QD + k0 + (t & 3) * 8], &Bs[t * 8]);
    ldg2lds16(&Bm[(size_t)(n0 + ((t + 256) >> 2)) * QD + k0 + (t & 3) * 8], &Bs[(t + 256) * 8]);
    __syncthreads();
    bf16x8 af[4], bfr[4];
#pragma unroll
    for (int m = 0; m < 4; m++)
      af[m] = *(const bf16x8*)&As[(wr * 64 + m * 16 + lr) * 32 + lg * 8];
#pragma unroll
    for (int n = 0; n < 4; n++)
      bfr[n] = *(const bf16x8*)&Bs[(wc * 64 + n * 16 + lr) * 32 + lg * 8];
#pragma unroll
    for (int m = 0; m < 4; m++)
#pragma unroll
      for (int n = 0; n < 4; n++)
        acc[m][n] = __builtin_amdgcn_mfma_f32_16x16x32_bf16(af[m], bfr[n], acc[m][n], 0, 0, 0);
    __syncthreads();
  }
#pragma unroll
  for (int m = 0; m < 4; m++) {
    int row = m0 + wr * 64 + m * 16 + lg * 4;
#pragma unroll
    for (int n = 0; n < 4; n++) {
      int col = n0 + wc * 64 + n * 16 + lr;
#pragma unroll
      for (int j = 0; j < 4; j++) {
        float v = acc[m][n][j];
        if constexpr (BF16OUT) {
          Cb[(size_t)(row + j) * QD + col] = f2bf(v);
        } else {
          Cf[(size_t)(row + j) * QD + col] = v + bias[col];
        }
      }
    }
  }
}

// ---------------- flash attention v6: uniform 2-strip blocks ----------------
// Same verified layouts/loop as attn3 (R4/R6 passing). Changes:
//  * Each block processes strips qt = s and qt = 15-s sequentially -> every
//    block = exactly 34 tile-units; grid (8,64)=512 uniform blocks, 2/CU.
//  * P-fragment assembly via v_permlane32_swap_b32 (replaces shfl+select;
//    mapping verified identical to R4's selection for hi=0/1).
//  * Staging pointers strength-reduced (advance per tile, same bytes).
//  * s_setprio(1) around MFMA clusters.
__global__ __launch_bounds__(256, 2) void k_attn6(
    const ushort_t* __restrict__ q, const ushort_t* __restrict__ qT,
    const float* __restrict__ kctx, const float* __restrict__ vctx,
    ushort_t* __restrict__ att) {
  const int s = blockIdx.x;        // 0..7
  const int bh = blockIdx.y;       // 0..63
  const int b = bh >> 4, h = bh & 15;
  const int t = threadIdx.x, w = t >> 6, l = t & 63;
  const int lq = l & 31, hi = l >> 5;

  __shared__ __align__(128) ushort_t Ks[2][4096];
  __shared__ __align__(128) ushort_t Vs[2][4096];

  const ushort_t* qbase = q + (size_t)b * N_ * QD + h * D_;
  const ushort_t* qtb = qT + (size_t)bh * D_ * N_;
  const float* kc = kctx + bh * D_;
  const float* vc = vctx + bh * D_;

  // per-thread staging geometry (loop-invariant)
  const int srow = t >> 3;
  const int scol = 8 * ((t & 7) ^ ((t >> 3) & 7));

#pragma unroll 1
  for (int pass = 0; pass < 2; ++pass) {
    const int qt = pass ? 15 - s : s;
    const int i0 = qt * 128;
    const int wq0 = i0 + w * 32;
    const int NT = 2 * qt + 2;

    // Q fragments (B-operand of S^T = K*Q^T)
    bf16x8 qf[4];
#pragma unroll
    for (int kk = 0; kk < 4; kk++)
      qf[kk] = *(const bf16x8*)&qbase[(size_t)(wq0 + lq) * QD + kk * 16 + hi * 8];

    // ctx token = softmax initializer (exp2 space)
    float m2, lsum;
    f32x16 oacc[2];
    {
      float dot = 0.f;
#pragma unroll
      for (int kk = 0; kk < 4; kk++)
#pragma unroll
        for (int j = 0; j < 8; j++)
          dot += (float)qf[kk][j] * kc[kk * 16 + hi * 8 + j];
      dot += __shfl_xor(dot, 32);
      m2 = dot * SC2;
      lsum = 1.0f;
#pragma unroll
      for (int dt = 0; dt < 2; dt++)
#pragma unroll
        for (int r = 0; r < 16; r++)
          oacc[dt][r] = vc[dt * 32 + (r & 3) + 8 * (r >> 2) + 4 * hi];
    }

    const ushort_t* stK = qbase + (size_t)srow * QD + scol;
    const ushort_t* stV = qtb + (size_t)srow * N_ + scol;

    // ---- stage tile 0 ----
    ldg2lds16(stK, &Ks[0][t * 8]);
    ldg2lds16(stK + (size_t)32 * QD, &Ks[0][(t + 256) * 8]);
    ldg2lds16(stV, &Vs[0][t * 8]);
    ldg2lds16(stV + (size_t)32 * N_, &Vs[0][(t + 256) * 8]);
    stK += (size_t)64 * QD;
    stV += 64;

    for (int tt = 0; tt < NT; ++tt) {
      const int cur = tt & 1;
      if (tt + 1 < NT) {
        ldg2lds16(stK, &Ks[cur ^ 1][t * 8]);
        ldg2lds16(stK + (size_t)32 * QD, &Ks[cur ^ 1][(t + 256) * 8]);
        ldg2lds16(stV, &Vs[cur ^ 1][t * 8]);
        ldg2lds16(stV + (size_t)32 * N_, &Vs[cur ^ 1][(t + 256) * 8]);
        stK += (size_t)64 * QD;
        stV += 64;
        asm volatile("s_waitcnt vmcnt(4)" ::: "memory");
      } else {
        asm volatile("s_waitcnt vmcnt(0)" ::: "memory");
      }
      __builtin_amdgcn_s_barrier();

      const int j0 = tt * 64;
      if (j0 <= wq0 + 31) {  // wave-level causal skip
        const char* ksb = (const char*)&Ks[cur][0];
        const char* vsb = (const char*)&Vs[cur][0];

        // ---- S^T = K * Q^T ----
        f32x16 p[2];
        __builtin_amdgcn_s_setprio(1);
#pragma unroll
        for (int kb = 0; kb < 2; kb++) {
          f32x16 acc;
#pragma unroll
          for (int r = 0; r < 16; r++) acc[r] = 0.f;
#pragma unroll
          for (int kk = 0; kk < 4; kk++) {
            bf16x8 kf = *(const bf16x8*)(ksb + (l & 31) * 128 + kb * 4096 +
                                         (((kk * 2 + hi) ^ (l & 7)) << 4));
            acc = __builtin_amdgcn_mfma_f32_32x32x16_bf16(kf, qf[kk], acc, 0, 0, 0);
          }
          p[kb] = acc;
        }
        __builtin_amdgcn_s_setprio(0);

        // ---- causal mask (diagonal tiles only) ----
        if (j0 + 63 > wq0) {
          const int qrel = wq0 - j0 + lq;
#pragma unroll
          for (int kb = 0; kb < 2; kb++)
#pragma unroll
            for (int r = 0; r < 16; r++) {
              int key = kb * 32 + (r & 3) + 8 * (r >> 2) + 4 * hi;
              if (key > qrel) p[kb][r] = -1e30f;
            }
        }

        // ---- online softmax (lane-local rows, exp2, defer-rescale) ----
        float rm = p[0][0];
#pragma unroll
        for (int r = 1; r < 16; r++) rm = fmaxf(rm, p[0][r]);
#pragma unroll
        for (int r = 0; r < 16; r++) rm = fmaxf(rm, p[1][r]);
        rm = fmaxf(rm, __shfl_xor(rm, 32));
        const float rmS = rm * SC2;
        if (!__all(rmS <= m2 + 8.0f)) {
          const float m2n = fmaxf(m2, rmS);
          const float corr = __builtin_exp2f(m2 - m2n);
          m2 = m2n;
          lsum *= corr;
#pragma unroll
          for (int dt = 0; dt < 2; dt++)
#pragma unroll
            for (int r = 0; r < 16; r++) oacc[dt][r] *= corr;
        }
        float rs = 0.f;
#pragma unroll
        for (int kb = 0; kb < 2; kb++)
#pragma unroll
          for (int r = 0; r < 16; r++) {
            float e = __builtin_exp2f(fmaf(p[kb][r], SC2, -m2));
            p[kb][r] = e;
            rs += e;
          }
        rs += __shfl_xor(rs, 32);
        lsum += rs;

        // ---- P -> bf16 B-fragments via permlane32_swap, then PV ----
#pragma unroll
        for (int kb = 0; kb < 2; kb++) {
          unsigned u[8];
#pragma unroll
          for (int i = 0; i < 8; i++) {
            union { __bf16 b2[2]; unsigned v; } pk2;
            pk2.b2[0] = (__bf16)p[kb][2 * i];
            pk2.b2[1] = (__bf16)p[kb][2 * i + 1];
            u[i] = pk2.v;
          }
          asm("v_permlane32_swap_b32 %0, %1" : "+v"(u[0]), "+v"(u[2]));
          asm("v_permlane32_swap_b32 %0, %1" : "+v"(u[1]), "+v"(u[3]));
          asm("v_permlane32_swap_b32 %0, %1" : "+v"(u[4]), "+v"(u[6]));
          asm("v_permlane32_swap_b32 %0, %1" : "+v"(u[5]), "+v"(u[7]));
          union { unsigned u4[4]; bf16x8 v; } pf0, pf1;
          pf0.u4[0] = u[0]; pf0.u4[1] = u[1]; pf0.u4[2] = u[2]; pf0.u4[3] = u[3];
          pf1.u4[0] = u[4]; pf1.u4[1] = u[5]; pf1.u4[2] = u[6]; pf1.u4[3] = u[7];
          __builtin_amdgcn_s_setprio(1);
#pragma unroll
          for (int ks = 0; ks < 2; ks++) {
            const bf16x8 pf = ks ? pf1.v : pf0.v;
#pragma unroll
            for (int dt = 0; dt < 2; dt++) {
              bf16x8 vf = *(const bf16x8*)(vsb + (l & 31) * 128 + dt * 4096 +
                                           (((kb * 4 + ks * 2 + hi) ^ (l & 7)) << 4));
              oacc[dt] = __builtin_amdgcn_mfma_f32_32x32x16_bf16(vf, pf, oacc[dt], 0, 0, 0);
            }
          }
          __builtin_amdgcn_s_setprio(0);
        }
      }
      __builtin_amdgcn_s_barrier();
    }

    // ---- epilogue: O^T regs -> att (bf16) for this strip ----
    const float inv = 1.0f / lsum;
    ushort_t* ob = att + (size_t)b * N_ * QD + (size_t)(wq0 + lq) * QD + h * D_;
#pragma unroll
    for (int dt = 0; dt < 2; dt++)
#pragma unroll
      for (int rq = 0; rq < 4; rq++) {
        union { ushort_t s4[4]; unsigned long long v; } o;
#pragma unroll
        for (int e = 0; e < 4; e++) o.s4[e] = bfbits(oacc[dt][rq * 4 + e] * inv);
        *(unsigned long long*)(ob + dt * 32 + 8 * rq + 4 * hi) = o.v;
      }
  }
}

extern "C" void kernel_launch(void* const* d_in, const int* in_sizes, int n_in,
                              void* d_out, int out_size, void* d_ws, size_t ws_size,
                              hipStream_t stream) {
  const float* x = (const float*)d_in[0];
  const float* ctx = (const float*)d_in[1];
  const float* Wq = (const float*)d_in[2];
  const float* Wk = (const float*)d_in[3];
  const float* Wv = (const float*)d_in[4];
  const float* Wo = (const float*)d_in[5];
  const float* bo = (const float*)d_in[6];
  float* out = (float*)d_out;

  char* ws = (char*)d_ws;
  size_t off = 0;
  ushort_t* xb = (ushort_t*)(ws + off);   off += (size_t)8192 * 1024 * 2;  // reused as qT
  ushort_t* qb = (ushort_t*)(ws + off);   off += (size_t)8192 * 1024 * 2;
  ushort_t* attb = (ushort_t*)(ws + off); off += (size_t)8192 * 1024 * 2;
  ushort_t* WqT = (ushort_t*)(ws + off);  off += (size_t)1024 * 1024 * 2;
  ushort_t* WoT = (ushort_t*)(ws + off);  off += (size_t)1024 * 1024 * 2;
  float* kctx = (float*)(ws + off);       off += (size_t)4096 * 4;
  float* vctx = (float*)(ws + off);       off += (size_t)4096 * 4;
  float* part = (float*)(ws + off);       off += (size_t)16 * 4096 * 4;
  ushort_t* qT = xb;  // xb is dead after k_gemm<1>

  k_cvt_bf16<<<dim3(4096), dim3(256), 0, stream>>>(x, xb, 8192 * 1024 / 8);
  k_transpose_w<<<dim3(16, 16, 2), dim3(256), 0, stream>>>(Wq, Wo, WqT, WoT);
  k_ctx_partial<<<dim3(4, 8, 2), dim3(256), 0, stream>>>(ctx, Wk, Wv, part);
  k_ctx_reduce<<<dim3(32), dim3(256), 0, stream>>>(part, kctx, vctx);
  k_gemm<1><<<dim3(8, 64), dim3(256), 0, stream>>>(xb, WqT, qb, nullptr, nullptr);
  k_transpose_q<<<dim3(32, 64), dim3(256), 0, stream>>>(qb, qT);
  k_attn6<<<dim3(8, 64), dim3(256), 0, stream>>>(qb, qT, kctx, vctx, attb);
  k_gemm<0><<<dim3(8, 64), dim3(256), 0, stream>>>(attb, WoT, nullptr, out, bo);
}

// Round 8
// 177.281 us; speedup vs baseline: 2.4483x; 1.0119x over previous
//
#include <hip/hip_runtime.h>
#include <stdint.h>

#define B_ 4
#define N_ 2048
#define H_ 16
#define D_ 64
#define QD 1024
#define SCALE 0.125f
#define LOG2E 1.44269504f
#define SC2 (SCALE * LOG2E)

typedef __bf16 bf16x8 __attribute__((ext_vector_type(8)));
typedef float f32x4 __attribute__((ext_vector_type(4)));
typedef float f32x16 __attribute__((ext_vector_type(16)));
typedef unsigned short u16x8 __attribute__((ext_vector_type(8)));
typedef unsigned short ushort_t;

__device__ __forceinline__ unsigned short f2bf(float f) {
  union { float f; unsigned u; } x; x.f = f;
  unsigned r = (x.u + 0x7fffu + ((x.u >> 16) & 1u)) >> 16;
  return (unsigned short)r;
}

__device__ __forceinline__ void ldg2lds16(const void* g, void* l) {
  __builtin_amdgcn_global_load_lds(
      (const __attribute__((address_space(1))) void*)g,
      (__attribute__((address_space(3))) void*)l, 16, 0, 0);
}

__device__ __forceinline__ ushort_t bfbits(float f) {
  union { __bf16 b; ushort_t u; } x; x.b = (__bf16)f; return x.u;
}

// ---------------- x fp32 -> bf16 ----------------
__global__ __launch_bounds__(256) void k_cvt_bf16(const float* __restrict__ in,
                                                  ushort_t* __restrict__ out, int n8) {
  int i = blockIdx.x * 256 + threadIdx.x;
  if (i >= n8) return;
  const float4* p = (const float4*)in + (size_t)i * 2;
  float4 a = p[0], b = p[1];
  u16x8 r;
  r[0] = f2bf(a.x); r[1] = f2bf(a.y); r[2] = f2bf(a.z); r[3] = f2bf(a.w);
  r[4] = f2bf(b.x); r[5] = f2bf(b.y); r[6] = f2bf(b.z); r[7] = f2bf(b.w);
  *((u16x8*)out + i) = r;
}

// ---------------- Wq,Wo transpose + convert: WT[n][k] = (bf16)W[k][n] ----------------
__global__ __launch_bounds__(256) void k_transpose_w(const float* __restrict__ Wq,
    const float* __restrict__ Wo, ushort_t* __restrict__ WqT, ushort_t* __restrict__ WoT) {
  const float* W = blockIdx.z ? Wo : Wq;
  ushort_t* WT = blockIdx.z ? WoT : WqT;
  __shared__ float tile[64][65];
  int n0 = blockIdx.x * 64, k0 = blockIdx.y * 64;
  int tx = threadIdx.x & 63, ty = threadIdx.x >> 6;
#pragma unroll
  for (int i = 0; i < 64; i += 4)
    tile[ty + i][tx] = W[(size_t)(k0 + ty + i) * QD + n0 + tx];
  __syncthreads();
#pragma unroll
  for (int i = 0; i < 64; i += 4)
    WT[(size_t)(n0 + ty + i) * QD + k0 + tx] = f2bf(tile[tx][ty + i]);
}

// ---------------- q [b][n][h*64+d] -> qT [bh][d][n] (bf16) ----------------
__global__ __launch_bounds__(256) void k_transpose_q(const ushort_t* __restrict__ qb,
                                                     ushort_t* __restrict__ qT) {
  const int bh = blockIdx.y, b = bh >> 4, h = bh & 15;
  const int n0 = blockIdx.x * 64;
  const int t = threadIdx.x;
  __shared__ ushort_t tile[64][72];
  const ushort_t* src = qb + ((size_t)b * N_ + n0) * QD + h * D_;
#pragma unroll
  for (int p = 0; p < 2; p++) {
    int r = (t >> 3) + p * 32;
    u16x8 v = *(const u16x8*)&src[(size_t)r * QD + (t & 7) * 8];
    *(u16x8*)&tile[r][(t & 7) * 8] = v;
  }
  __syncthreads();
  ushort_t* dst = qT + (size_t)bh * D_ * N_ + n0;
#pragma unroll
  for (int p = 0; p < 2; p++) {
    int d = (t >> 3) + p * 32;
    union { ushort_t s[8]; u16x8 v; } o;
#pragma unroll
    for (int e = 0; e < 8; e++) o.s[e] = tile[(t & 7) * 8 + e][d];
    *(u16x8*)&dst[(size_t)d * N_ + (t & 7) * 8] = o.v;
  }
}

// ---------------- ctx projections ----------------
__global__ __launch_bounds__(256) void k_ctx_partial(const float* __restrict__ ctx,
    const float* __restrict__ Wk, const float* __restrict__ Wv, float* __restrict__ part) {
  int ich = blockIdx.x;
  int ks = blockIdx.y;
  int kv = blockIdx.z;
  const float* W = kv ? Wv : Wk;
  __shared__ float cs[B_][128];
  int t = threadIdx.x;
  for (int i = t; i < B_ * 128; i += 256)
    cs[i >> 7][i & 127] = ctx[(size_t)(i >> 7) * QD + ks * 128 + (i & 127)];
  __syncthreads();
  int col = ich * 256 + t;
  float a0 = 0, a1 = 0, a2 = 0, a3 = 0;
  for (int k = 0; k < 128; k++) {
    float w = W[(size_t)(ks * 128 + k) * QD + col];
    a0 += cs[0][k] * w; a1 += cs[1][k] * w; a2 += cs[2][k] * w; a3 += cs[3][k] * w;
  }
  float* p = part + (size_t)(ks * 2 + kv) * (B_ * QD);
  p[0 * QD + col] = a0; p[1 * QD + col] = a1; p[2 * QD + col] = a2; p[3 * QD + col] = a3;
}

__global__ __launch_bounds__(256) void k_ctx_reduce(const float* __restrict__ part,
    float* __restrict__ kctx, float* __restrict__ vctx) {
  int idx = blockIdx.x * 256 + threadIdx.x;
  int kv = idx >> 12;
  int rest = idx & 4095;
  float acc = 0;
  for (int ks = 0; ks < 8; ks++) acc += part[(size_t)(ks * 2 + kv) * 4096 + rest];
  (kv ? vctx : kctx)[rest] = acc;
}

// ---------------- bf16 GEMM: C[M][1024] = A[M][1024] @ B^T ----------------
template <int BF16OUT>
__global__ __launch_bounds__(256) void k_gemm(const ushort_t* __restrict__ A,
    const ushort_t* __restrict__ Bm, ushort_t* __restrict__ Cb, float* __restrict__ Cf,
    const float* __restrict__ bias) {
  __shared__ ushort_t As[128 * 32];
  __shared__ ushort_t Bs[128 * 32];
  const int t = threadIdx.x;
  const int w = t >> 6, l = t & 63;
  const int wr = w >> 1, wc = w & 1;
  const int lr = l & 15, lg = l >> 4;
  const int m0 = blockIdx.y * 128, n0 = blockIdx.x * 128;
  f32x4 acc[4][4] = {};
  for (int k0 = 0; k0 < QD; k0 += 32) {
    ldg2lds16(&A[(size_t)(m0 + (t >> 2)) * QD + k0 + (t & 3) * 8], &As[t * 8]);
    ldg2lds16(&A[(size_t)(m0 + ((t + 256) >> 2)) * QD + k0 + (t & 3) * 8], &As[(t + 256) * 8]);
    ldg2lds16(&Bm[(size_t)(n0 + (t >> 2)) * QD + k0 + (t & 3) * 8], &Bs[t * 8]);
    ldg2lds16(&Bm[(size_t)(n0 + ((t + 256) >> 2)) * QD + k0 + (t & 3) * 8], &Bs[(t + 256) * 8]);
    __syncthreads();
    bf16x8 af[4], bfr[4];
#pragma unroll
    for (int m = 0; m < 4; m++)
      af[m] = *(const bf16x8*)&As[(wr * 64 + m * 16 + lr) * 32 + lg * 8];
#pragma unroll
    for (int n = 0; n < 4; n++)
      bfr[n] = *(const bf16x8*)&Bs[(wc * 64 + n * 16 + lr) * 32 + lg * 8];
#pragma unroll
    for (int m = 0; m < 4; m++)
#pragma unroll
      for (int n = 0; n < 4; n++)
        acc[m][n] = __builtin_amdgcn_mfma_f32_16x16x32_bf16(af[m], bfr[n], acc[m][n], 0, 0, 0);
    __syncthreads();
  }
#pragma unroll
  for (int m = 0; m < 4; m++) {
    int row = m0 + wr * 64 + m * 16 + lg * 4;
#pragma unroll
    for (int n = 0; n < 4; n++) {
      int col = n0 + wc * 64 + n * 16 + lr;
#pragma unroll
      for (int j = 0; j < 4; j++) {
        float v = acc[m][n][j];
        if constexpr (BF16OUT) {
          Cb[(size_t)(row + j) * QD + col] = f2bf(v);
        } else {
          Cf[(size_t)(row + j) * QD + col] = v + bias[col];
        }
      }
    }
  }
}

// ---------------- flash attention v7: 4-deep ring, 1 barrier/tile ----------------
// Same verified layouts & compute as R7's k_attn6. Pipeline changes only:
//  * K/V LDS ring of 4 buffers (64 KB); stage tile k+2 at tile k (2-deep).
//  * ONE s_barrier per tile: write target (k+2)&3 was last read at k-2 and
//    barrier(k-1) proves all waves passed that compute; per-wave vmcnt before
//    barrier(k) publishes all DMA for tile k.
//  * Counted drains: vmcnt(8) steady / 4 / 0 at the tail (never over-drain).
//  * Per-pass entry barrier protects ring reuse across the two strips.
__global__ __launch_bounds__(256, 2) void k_attn7(
    const ushort_t* __restrict__ q, const ushort_t* __restrict__ qT,
    const float* __restrict__ kctx, const float* __restrict__ vctx,
    ushort_t* __restrict__ att) {
  const int s = blockIdx.x;        // 0..7
  const int bh = blockIdx.y;       // 0..63
  const int b = bh >> 4, h = bh & 15;
  const int t = threadIdx.x, w = t >> 6, l = t & 63;
  const int lq = l & 31, hi = l >> 5;

  __shared__ __align__(128) ushort_t Ks[4][4096];
  __shared__ __align__(128) ushort_t Vs[4][4096];

  const ushort_t* qbase = q + (size_t)b * N_ * QD + h * D_;
  const ushort_t* qtb = qT + (size_t)bh * D_ * N_;
  const float* kc = kctx + bh * D_;
  const float* vc = vctx + bh * D_;

  // per-thread staging geometry (loop-invariant)
  const int srow = t >> 3;
  const int scol = 8 * ((t & 7) ^ ((t >> 3) & 7));

#pragma unroll 1
  for (int pass = 0; pass < 2; ++pass) {
    const int qt = pass ? 15 - s : s;
    const int i0 = qt * 128;
    const int wq0 = i0 + w * 32;
    const int NT = 2 * qt + 2;

    __builtin_amdgcn_s_barrier();  // ring-buffer lifetime across passes

    // ---- prologue: stage tiles 0 and 1 (NT >= 2 always) ----
    const ushort_t* stK = qbase + (size_t)srow * QD + scol;
    const ushort_t* stV = qtb + (size_t)srow * N_ + scol;
    ldg2lds16(stK, &Ks[0][t * 8]);
    ldg2lds16(stK + (size_t)32 * QD, &Ks[0][(t + 256) * 8]);
    ldg2lds16(stV, &Vs[0][t * 8]);
    ldg2lds16(stV + (size_t)32 * N_, &Vs[0][(t + 256) * 8]);
    ldg2lds16(stK + (size_t)64 * QD, &Ks[1][t * 8]);
    ldg2lds16(stK + (size_t)96 * QD, &Ks[1][(t + 256) * 8]);
    ldg2lds16(stV + 64, &Vs[1][t * 8]);
    ldg2lds16(stV + (size_t)32 * N_ + 64, &Vs[1][(t + 256) * 8]);
    stK += (size_t)128 * QD;
    stV += 128;

    // ---- Q fragments + ctx init (overlaps prologue DMA latency) ----
    bf16x8 qf[4];
#pragma unroll
    for (int kk = 0; kk < 4; kk++)
      qf[kk] = *(const bf16x8*)&qbase[(size_t)(wq0 + lq) * QD + kk * 16 + hi * 8];

    float m2, lsum;
    f32x16 oacc[2];
    {
      float dot = 0.f;
#pragma unroll
      for (int kk = 0; kk < 4; kk++)
#pragma unroll
        for (int j = 0; j < 8; j++)
          dot += (float)qf[kk][j] * kc[kk * 16 + hi * 8 + j];
      dot += __shfl_xor(dot, 32);
      m2 = dot * SC2;
      lsum = 1.0f;
#pragma unroll
      for (int dt = 0; dt < 2; dt++)
#pragma unroll
        for (int r = 0; r < 16; r++)
          oacc[dt][r] = vc[dt * 32 + (r & 3) + 8 * (r >> 2) + 4 * hi];
    }

    for (int tt = 0; tt < NT; ++tt) {
      const int cur = tt & 3;
      if (tt + 2 < NT) {
        ushort_t* kd = &Ks[(tt + 2) & 3][0];
        ushort_t* vd = &Vs[(tt + 2) & 3][0];
        ldg2lds16(stK, kd + t * 8);
        ldg2lds16(stK + (size_t)32 * QD, kd + (t + 256) * 8);
        ldg2lds16(stV, vd + t * 8);
        ldg2lds16(stV + (size_t)32 * N_, vd + (t + 256) * 8);
        stK += (size_t)64 * QD;
        stV += 64;
        asm volatile("s_waitcnt vmcnt(8)" ::: "memory");
      } else if (tt + 1 < NT) {
        asm volatile("s_waitcnt vmcnt(4)" ::: "memory");
      } else {
        asm volatile("s_waitcnt vmcnt(0)" ::: "memory");
      }
      __builtin_amdgcn_s_barrier();

      const int j0 = tt * 64;
      if (j0 <= wq0 + 31) {  // wave-level causal skip
        const char* ksb = (const char*)&Ks[cur][0];
        const char* vsb = (const char*)&Vs[cur][0];

        // ---- S^T = K * Q^T ----
        f32x16 p[2];
        __builtin_amdgcn_s_setprio(1);
#pragma unroll
        for (int kb = 0; kb < 2; kb++) {
          f32x16 acc;
#pragma unroll
          for (int r = 0; r < 16; r++) acc[r] = 0.f;
#pragma unroll
          for (int kk = 0; kk < 4; kk++) {
            bf16x8 kf = *(const bf16x8*)(ksb + (l & 31) * 128 + kb * 4096 +
                                         (((kk * 2 + hi) ^ (l & 7)) << 4));
            acc = __builtin_amdgcn_mfma_f32_32x32x16_bf16(kf, qf[kk], acc, 0, 0, 0);
          }
          p[kb] = acc;
        }
        __builtin_amdgcn_s_setprio(0);

        // ---- causal mask (diagonal tiles only) ----
        if (j0 + 63 > wq0) {
          const int qrel = wq0 - j0 + lq;
#pragma unroll
          for (int kb = 0; kb < 2; kb++)
#pragma unroll
            for (int r = 0; r < 16; r++) {
              int key = kb * 32 + (r & 3) + 8 * (r >> 2) + 4 * hi;
              if (key > qrel) p[kb][r] = -1e30f;
            }
        }

        // ---- online softmax (lane-local rows, exp2, defer-rescale) ----
        float rm = p[0][0];
#pragma unroll
        for (int r = 1; r < 16; r++) rm = fmaxf(rm, p[0][r]);
#pragma unroll
        for (int r = 0; r < 16; r++) rm = fmaxf(rm, p[1][r]);
        rm = fmaxf(rm, __shfl_xor(rm, 32));
        const float rmS = rm * SC2;
        if (!__all(rmS <= m2 + 8.0f)) {
          const float m2n = fmaxf(m2, rmS);
          const float corr = __builtin_exp2f(m2 - m2n);
          m2 = m2n;
          lsum *= corr;
#pragma unroll
          for (int dt = 0; dt < 2; dt++)
#pragma unroll
            for (int r = 0; r < 16; r++) oacc[dt][r] *= corr;
        }
        float rs = 0.f;
#pragma unroll
        for (int kb = 0; kb < 2; kb++)
#pragma unroll
          for (int r = 0; r < 16; r++) {
            float e = __builtin_exp2f(fmaf(p[kb][r], SC2, -m2));
            p[kb][r] = e;
            rs += e;
          }
        rs += __shfl_xor(rs, 32);
        lsum += rs;

        // ---- P -> bf16 B-fragments via permlane32_swap, then PV ----
#pragma unroll
        for (int kb = 0; kb < 2; kb++) {
          unsigned u[8];
#pragma unroll
          for (int i = 0; i < 8; i++) {
            union { __bf16 b2[2]; unsigned v; } pk2;
            pk2.b2[0] = (__bf16)p[kb][2 * i];
            pk2.b2[1] = (__bf16)p[kb][2 * i + 1];
            u[i] = pk2.v;
          }
          asm("v_permlane32_swap_b32 %0, %1" : "+v"(u[0]), "+v"(u[2]));
          asm("v_permlane32_swap_b32 %0, %1" : "+v"(u[1]), "+v"(u[3]));
          asm("v_permlane32_swap_b32 %0, %1" : "+v"(u[4]), "+v"(u[6]));
          asm("v_permlane32_swap_b32 %0, %1" : "+v"(u[5]), "+v"(u[7]));
          union { unsigned u4[4]; bf16x8 v; } pf0, pf1;
          pf0.u4[0] = u[0]; pf0.u4[1] = u[1]; pf0.u4[2] = u[2]; pf0.u4[3] = u[3];
          pf1.u4[0] = u[4]; pf1.u4[1] = u[5]; pf1.u4[2] = u[6]; pf1.u4[3] = u[7];
          __builtin_amdgcn_s_setprio(1);
#pragma unroll
          for (int ks = 0; ks < 2; ks++) {
            const bf16x8 pf = ks ? pf1.v : pf0.v;
#pragma unroll
            for (int dt = 0; dt < 2; dt++) {
              bf16x8 vf = *(const bf16x8*)(vsb + (l & 31) * 128 + dt * 4096 +
                                           (((kb * 4 + ks * 2 + hi) ^ (l & 7)) << 4));
              oacc[dt] = __builtin_amdgcn_mfma_f32_32x32x16_bf16(vf, pf, oacc[dt], 0, 0, 0);
            }
          }
          __builtin_amdgcn_s_setprio(0);
        }
      }
    }

    // ---- epilogue: O^T regs -> att (bf16) for this strip ----
    const float inv = 1.0f / lsum;
    ushort_t* ob = att + (size_t)b * N_ * QD + (size_t)(wq0 + lq) * QD + h * D_;
#pragma unroll
    for (int dt = 0; dt < 2; dt++)
#pragma unroll
      for (int rq = 0; rq < 4; rq++) {
        union { ushort_t s4[4]; unsigned long long v; } o;
#pragma unroll
        for (int e = 0; e < 4; e++) o.s4[e] = bfbits(oacc[dt][rq * 4 + e] * inv);
        *(unsigned long long*)(ob + dt * 32 + 8 * rq + 4 * hi) = o.v;
      }
  }
}

extern "C" void kernel_launch(void* const* d_in, const int* in_sizes, int n_in,
                              void* d_out, int out_size, void* d_ws, size_t ws_size,
                              hipStream_t stream) {
  const float* x = (const float*)d_in[0];
  const float* ctx = (const float*)d_in[1];
  const float* Wq = (const float*)d_in[2];
  const float* Wk = (const float*)d_in[3];
  const float* Wv = (const float*)d_in[4];
  const float* Wo = (const float*)d_in[5];
  const float* bo = (const float*)d_in[6];
  float* out = (float*)d_out;

  char* ws = (char*)d_ws;
  size_t off = 0;
  ushort_t* xb = (ushort_t*)(ws + off);   off += (size_t)8192 * 1024 * 2;  // reused as qT
  ushort_t* qb = (ushort_t*)(ws + off);   off += (size_t)8192 * 1024 * 2;
  ushort_t* attb = (ushort_t*)(ws + off); off += (size_t)8192 * 1024 * 2;
  ushort_t* WqT = (ushort_t*)(ws + off);  off += (size_t)1024 * 1024 * 2;
  ushort_t* WoT = (ushort_t*)(ws + off);  off += (size_t)1024 * 1024 * 2;
  float* kctx = (float*)(ws + off);       off += (size_t)4096 * 4;
  float* vctx = (float*)(ws + off);       off += (size_t)4096 * 4;
  float* part = (float*)(ws + off);       off += (size_t)16 * 4096 * 4;
  ushort_t* qT = xb;  // xb is dead after k_gemm<1>

  k_cvt_bf16<<<dim3(4096), dim3(256), 0, stream>>>(x, xb, 8192 * 1024 / 8);
  k_transpose_w<<<dim3(16, 16, 2), dim3(256), 0, stream>>>(Wq, Wo, WqT, WoT);
  k_ctx_partial<<<dim3(4, 8, 2), dim3(256), 0, stream>>>(ctx, Wk, Wv, part);
  k_ctx_reduce<<<dim3(32), dim3(256), 0, stream>>>(part, kctx, vctx);
  k_gemm<1><<<dim3(8, 64), dim3(256), 0, stream>>>(xb, WqT, qb, nullptr, nullptr);
  k_transpose_q<<<dim3(32, 64), dim3(256), 0, stream>>>(qb, qT);
  k_attn7<<<dim3(8, 64), dim3(256), 0, stream>>>(qb, qT, kctx, vctx, attb);
  k_gemm<0><<<dim3(8, 64), dim3(256), 0, stream>>>(attb, WoT, nullptr, out, bo);
}

// Round 9
// 172.267 us; speedup vs baseline: 2.5196x; 1.0291x over previous
//
#include <hip/hip_runtime.h>
#include <stdint.h>

#define B_ 4
#define N_ 2048
#define H_ 16
#define D_ 64
#define QD 1024
#define SCALE 0.125f
#define LOG2E 1.44269504f
#define SC2 (SCALE * LOG2E)

typedef __bf16 bf16x8 __attribute__((ext_vector_type(8)));
typedef float f32x4 __attribute__((ext_vector_type(4)));
typedef float f32x16 __attribute__((ext_vector_type(16)));
typedef unsigned short u16x8 __attribute__((ext_vector_type(8)));
typedef unsigned short ushort_t;

__device__ __forceinline__ unsigned short f2bf(float f) {
  union { float f; unsigned u; } x; x.f = f;
  unsigned r = (x.u + 0x7fffu + ((x.u >> 16) & 1u)) >> 16;
  return (unsigned short)r;
}

__device__ __forceinline__ void ldg2lds16(const void* g, void* l) {
  __builtin_amdgcn_global_load_lds(
      (const __attribute__((address_space(1))) void*)g,
      (__attribute__((address_space(3))) void*)l, 16, 0, 0);
}

__device__ __forceinline__ ushort_t bfbits(float f) {
  union { __bf16 b; ushort_t u; } x; x.b = (__bf16)f; return x.u;
}

// ---------------- x fp32 -> bf16 ----------------
__global__ __launch_bounds__(256) void k_cvt_bf16(const float* __restrict__ in,
                                                  ushort_t* __restrict__ out, int n8) {
  int i = blockIdx.x * 256 + threadIdx.x;
  if (i >= n8) return;
  const float4* p = (const float4*)in + (size_t)i * 2;
  float4 a = p[0], b = p[1];
  u16x8 r;
  r[0] = f2bf(a.x); r[1] = f2bf(a.y); r[2] = f2bf(a.z); r[3] = f2bf(a.w);
  r[4] = f2bf(b.x); r[5] = f2bf(b.y); r[6] = f2bf(b.z); r[7] = f2bf(b.w);
  *((u16x8*)out + i) = r;
}

// ---------------- Wq,Wo transpose + convert: WT[n][k] = (bf16)W[k][n] ----------------
__global__ __launch_bounds__(256) void k_transpose_w(const float* __restrict__ Wq,
    const float* __restrict__ Wo, ushort_t* __restrict__ WqT, ushort_t* __restrict__ WoT) {
  const float* W = blockIdx.z ? Wo : Wq;
  ushort_t* WT = blockIdx.z ? WoT : WqT;
  __shared__ float tile[64][65];
  int n0 = blockIdx.x * 64, k0 = blockIdx.y * 64;
  int tx = threadIdx.x & 63, ty = threadIdx.x >> 6;
#pragma unroll
  for (int i = 0; i < 64; i += 4)
    tile[ty + i][tx] = W[(size_t)(k0 + ty + i) * QD + n0 + tx];
  __syncthreads();
#pragma unroll
  for (int i = 0; i < 64; i += 4)
    WT[(size_t)(n0 + ty + i) * QD + k0 + tx] = f2bf(tile[tx][ty + i]);
}

// ---------------- q [b][n][h*64+d] -> qT [bh][d][n] (bf16) ----------------
__global__ __launch_bounds__(256) void k_transpose_q(const ushort_t* __restrict__ qb,
                                                     ushort_t* __restrict__ qT) {
  const int bh = blockIdx.y, b = bh >> 4, h = bh & 15;
  const int n0 = blockIdx.x * 64;
  const int t = threadIdx.x;
  __shared__ ushort_t tile[64][72];
  const ushort_t* src = qb + ((size_t)b * N_ + n0) * QD + h * D_;
#pragma unroll
  for (int p = 0; p < 2; p++) {
    int r = (t >> 3) + p * 32;
    u16x8 v = *(const u16x8*)&src[(size_t)r * QD + (t & 7) * 8];
    *(u16x8*)&tile[r][(t & 7) * 8] = v;
  }
  __syncthreads();
  ushort_t* dst = qT + (size_t)bh * D_ * N_ + n0;
#pragma unroll
  for (int p = 0; p < 2; p++) {
    int d = (t >> 3) + p * 32;
    union { ushort_t s[8]; u16x8 v; } o;
#pragma unroll
    for (int e = 0; e < 8; e++) o.s[e] = tile[(t & 7) * 8 + e][d];
    *(u16x8*)&dst[(size_t)d * N_ + (t & 7) * 8] = o.v;
  }
}

// ---------------- ctx projections ----------------
__global__ __launch_bounds__(256) void k_ctx_partial(const float* __restrict__ ctx,
    const float* __restrict__ Wk, const float* __restrict__ Wv, float* __restrict__ part) {
  int ich = blockIdx.x;
  int ks = blockIdx.y;
  int kv = blockIdx.z;
  const float* W = kv ? Wv : Wk;
  __shared__ float cs[B_][128];
  int t = threadIdx.x;
  for (int i = t; i < B_ * 128; i += 256)
    cs[i >> 7][i & 127] = ctx[(size_t)(i >> 7) * QD + ks * 128 + (i & 127)];
  __syncthreads();
  int col = ich * 256 + t;
  float a0 = 0, a1 = 0, a2 = 0, a3 = 0;
  for (int k = 0; k < 128; k++) {
    float w = W[(size_t)(ks * 128 + k) * QD + col];
    a0 += cs[0][k] * w; a1 += cs[1][k] * w; a2 += cs[2][k] * w; a3 += cs[3][k] * w;
  }
  float* p = part + (size_t)(ks * 2 + kv) * (B_ * QD);
  p[0 * QD + col] = a0; p[1 * QD + col] = a1; p[2 * QD + col] = a2; p[3 * QD + col] = a3;
}

__global__ __launch_bounds__(256) void k_ctx_reduce(const float* __restrict__ part,
    float* __restrict__ kctx, float* __restrict__ vctx) {
  int idx = blockIdx.x * 256 + threadIdx.x;
  int kv = idx >> 12;
  int rest = idx & 4095;
  float acc = 0;
  for (int ks = 0; ks < 8; ks++) acc += part[(size_t)(ks * 2 + kv) * 4096 + rest];
  (kv ? vctx : kctx)[rest] = acc;
}

// ---------------- bf16 GEMM: C[M][1024] = A[M][1024] @ B^T ----------------
template <int BF16OUT>
__global__ __launch_bounds__(256) void k_gemm(const ushort_t* __restrict__ A,
    const ushort_t* __restrict__ Bm, ushort_t* __restrict__ Cb, float* __restrict__ Cf,
    const float* __restrict__ bias) {
  __shared__ ushort_t As[128 * 32];
  __shared__ ushort_t Bs[128 * 32];
  const int t = threadIdx.x;
  const int w = t >> 6, l = t & 63;
  const int wr = w >> 1, wc = w & 1;
  const int lr = l & 15, lg = l >> 4;
  const int m0 = blockIdx.y * 128, n0 = blockIdx.x * 128;
  f32x4 acc[4][4] = {};
  for (int k0 = 0; k0 < QD; k0 += 32) {
    ldg2lds16(&A[(size_t)(m0 + (t >> 2)) * QD + k0 + (t & 3) * 8], &As[t * 8]);
    ldg2lds16(&A[(size_t)(m0 + ((t + 256) >> 2)) * QD + k0 + (t & 3) * 8], &As[(t + 256) * 8]);
    ldg2lds16(&Bm[(size_t)(n0 + (t >> 2)) * QD + k0 + (t & 3) * 8], &Bs[t * 8]);
    ldg2lds16(&Bm[(size_t)(n0 + ((t + 256) >> 2)) * QD + k0 + (t & 3) * 8], &Bs[(t + 256) * 8]);
    __syncthreads();
    bf16x8 af[4], bfr[4];
#pragma unroll
    for (int m = 0; m < 4; m++)
      af[m] = *(const bf16x8*)&As[(wr * 64 + m * 16 + lr) * 32 + lg * 8];
#pragma unroll
    for (int n = 0; n < 4; n++)
      bfr[n] = *(const bf16x8*)&Bs[(wc * 64 + n * 16 + lr) * 32 + lg * 8];
#pragma unroll
    for (int m = 0; m < 4; m++)
#pragma unroll
      for (int n = 0; n < 4; n++)
        acc[m][n] = __builtin_amdgcn_mfma_f32_16x16x32_bf16(af[m], bfr[n], acc[m][n], 0, 0, 0);
    __syncthreads();
  }
#pragma unroll
  for (int m = 0; m < 4; m++) {
    int row = m0 + wr * 64 + m * 16 + lg * 4;
#pragma unroll
    for (int n = 0; n < 4; n++) {
      int col = n0 + wc * 64 + n * 16 + lr;
#pragma unroll
      for (int j = 0; j < 4; j++) {
        float v = acc[m][n][j];
        if constexpr (BF16OUT) {
          Cb[(size_t)(row + j) * QD + col] = f2bf(v);
        } else {
          Cf[(size_t)(row + j) * QD + col] = v + bias[col];
        }
      }
    }
  }
}

// ---------------- flash attention v8: XCD-local bh grouping + tree reductions ----
// Pipeline identical to R8's k_attn7 (4-deep ring, 1 barrier/tile, counted
// vmcnt). Changes:
//  * 1D grid 512; wg -> s = wg>>6, bh = ((wg&7)<<3)|((wg>>3)&7). Under
//    round-robin XCD dispatch (wg%8 = XCD), each XCD sees 8 consecutive bh
//    -> per-XCD K+V working set = 4 MB = L2 size (was 32 MB thrash).
//  * rm / rs reductions as depth-5 balanced trees (were 31/32-deep serial).
__global__ __launch_bounds__(256, 2) void k_attn8(
    const ushort_t* __restrict__ q, const ushort_t* __restrict__ qT,
    const float* __restrict__ kctx, const float* __restrict__ vctx,
    ushort_t* __restrict__ att) {
  const int wg = blockIdx.x;
  const int s = wg >> 6;                              // 0..7
  const int bh = ((wg & 7) << 3) | ((wg >> 3) & 7);   // 0..63, XCD-grouped
  const int b = bh >> 4, h = bh & 15;
  const int t = threadIdx.x, w = t >> 6, l = t & 63;
  const int lq = l & 31, hi = l >> 5;

  __shared__ __align__(128) ushort_t Ks[4][4096];
  __shared__ __align__(128) ushort_t Vs[4][4096];

  const ushort_t* qbase = q + (size_t)b * N_ * QD + h * D_;
  const ushort_t* qtb = qT + (size_t)bh * D_ * N_;
  const float* kc = kctx + bh * D_;
  const float* vc = vctx + bh * D_;

  // per-thread staging geometry (loop-invariant)
  const int srow = t >> 3;
  const int scol = 8 * ((t & 7) ^ ((t >> 3) & 7));

#pragma unroll 1
  for (int pass = 0; pass < 2; ++pass) {
    const int qt = pass ? 15 - s : s;
    const int i0 = qt * 128;
    const int wq0 = i0 + w * 32;
    const int NT = 2 * qt + 2;

    __builtin_amdgcn_s_barrier();  // ring-buffer lifetime across passes

    // ---- prologue: stage tiles 0 and 1 (NT >= 2 always) ----
    const ushort_t* stK = qbase + (size_t)srow * QD + scol;
    const ushort_t* stV = qtb + (size_t)srow * N_ + scol;
    ldg2lds16(stK, &Ks[0][t * 8]);
    ldg2lds16(stK + (size_t)32 * QD, &Ks[0][(t + 256) * 8]);
    ldg2lds16(stV, &Vs[0][t * 8]);
    ldg2lds16(stV + (size_t)32 * N_, &Vs[0][(t + 256) * 8]);
    ldg2lds16(stK + (size_t)64 * QD, &Ks[1][t * 8]);
    ldg2lds16(stK + (size_t)96 * QD, &Ks[1][(t + 256) * 8]);
    ldg2lds16(stV + 64, &Vs[1][t * 8]);
    ldg2lds16(stV + (size_t)32 * N_ + 64, &Vs[1][(t + 256) * 8]);
    stK += (size_t)128 * QD;
    stV += 128;

    // ---- Q fragments + ctx init (overlaps prologue DMA latency) ----
    bf16x8 qf[4];
#pragma unroll
    for (int kk = 0; kk < 4; kk++)
      qf[kk] = *(const bf16x8*)&qbase[(size_t)(wq0 + lq) * QD + kk * 16 + hi * 8];

    float m2, lsum;
    f32x16 oacc[2];
    {
      float dot = 0.f;
#pragma unroll
      for (int kk = 0; kk < 4; kk++)
#pragma unroll
        for (int j = 0; j < 8; j++)
          dot += (float)qf[kk][j] * kc[kk * 16 + hi * 8 + j];
      dot += __shfl_xor(dot, 32);
      m2 = dot * SC2;
      lsum = 1.0f;
#pragma unroll
      for (int dt = 0; dt < 2; dt++)
#pragma unroll
        for (int r = 0; r < 16; r++)
          oacc[dt][r] = vc[dt * 32 + (r & 3) + 8 * (r >> 2) + 4 * hi];
    }

    for (int tt = 0; tt < NT; ++tt) {
      const int cur = tt & 3;
      if (tt + 2 < NT) {
        ushort_t* kd = &Ks[(tt + 2) & 3][0];
        ushort_t* vd = &Vs[(tt + 2) & 3][0];
        ldg2lds16(stK, kd + t * 8);
        ldg2lds16(stK + (size_t)32 * QD, kd + (t + 256) * 8);
        ldg2lds16(stV, vd + t * 8);
        ldg2lds16(stV + (size_t)32 * N_, vd + (t + 256) * 8);
        stK += (size_t)64 * QD;
        stV += 64;
        asm volatile("s_waitcnt vmcnt(8)" ::: "memory");
      } else if (tt + 1 < NT) {
        asm volatile("s_waitcnt vmcnt(4)" ::: "memory");
      } else {
        asm volatile("s_waitcnt vmcnt(0)" ::: "memory");
      }
      __builtin_amdgcn_s_barrier();

      const int j0 = tt * 64;
      if (j0 <= wq0 + 31) {  // wave-level causal skip
        const char* ksb = (const char*)&Ks[cur][0];
        const char* vsb = (const char*)&Vs[cur][0];

        // ---- S^T = K * Q^T ----
        f32x16 p[2];
        __builtin_amdgcn_s_setprio(1);
#pragma unroll
        for (int kb = 0; kb < 2; kb++) {
          f32x16 acc;
#pragma unroll
          for (int r = 0; r < 16; r++) acc[r] = 0.f;
#pragma unroll
          for (int kk = 0; kk < 4; kk++) {
            bf16x8 kf = *(const bf16x8*)(ksb + (l & 31) * 128 + kb * 4096 +
                                         (((kk * 2 + hi) ^ (l & 7)) << 4));
            acc = __builtin_amdgcn_mfma_f32_32x32x16_bf16(kf, qf[kk], acc, 0, 0, 0);
          }
          p[kb] = acc;
        }
        __builtin_amdgcn_s_setprio(0);

        // ---- causal mask (diagonal tiles only) ----
        if (j0 + 63 > wq0) {
          const int qrel = wq0 - j0 + lq;
#pragma unroll
          for (int kb = 0; kb < 2; kb++)
#pragma unroll
            for (int r = 0; r < 16; r++) {
              int key = kb * 32 + (r & 3) + 8 * (r >> 2) + 4 * hi;
              if (key > qrel) p[kb][r] = -1e30f;
            }
        }

        // ---- online softmax: balanced-tree max, exp2, defer-rescale ----
        float x8[8];
#pragma unroll
        for (int r = 0; r < 8; r++)
          x8[r] = fmaxf(fmaxf(p[0][r], p[0][r + 8]), fmaxf(p[1][r], p[1][r + 8]));
        float x4a = fmaxf(x8[0], x8[4]), x4b = fmaxf(x8[1], x8[5]);
        float x4c = fmaxf(x8[2], x8[6]), x4d = fmaxf(x8[3], x8[7]);
        float rm = fmaxf(fmaxf(x4a, x4b), fmaxf(x4c, x4d));
        rm = fmaxf(rm, __shfl_xor(rm, 32));
        const float rmS = rm * SC2;
        if (!__all(rmS <= m2 + 8.0f)) {
          const float m2n = fmaxf(m2, rmS);
          const float corr = __builtin_exp2f(m2 - m2n);
          m2 = m2n;
          lsum *= corr;
#pragma unroll
          for (int dt = 0; dt < 2; dt++)
#pragma unroll
            for (int r = 0; r < 16; r++) oacc[dt][r] *= corr;
        }
#pragma unroll
        for (int kb = 0; kb < 2; kb++)
#pragma unroll
          for (int r = 0; r < 16; r++)
            p[kb][r] = __builtin_exp2f(fmaf(p[kb][r], SC2, -m2));
        float s8[8];
#pragma unroll
        for (int r = 0; r < 8; r++)
          s8[r] = (p[0][r] + p[0][r + 8]) + (p[1][r] + p[1][r + 8]);
        float s4a = s8[0] + s8[4], s4b = s8[1] + s8[5];
        float s4c = s8[2] + s8[6], s4d = s8[3] + s8[7];
        float rs = (s4a + s4b) + (s4c + s4d);
        rs += __shfl_xor(rs, 32);
        lsum += rs;

        // ---- P -> bf16 B-fragments via permlane32_swap, then PV ----
#pragma unroll
        for (int kb = 0; kb < 2; kb++) {
          unsigned u[8];
#pragma unroll
          for (int i = 0; i < 8; i++) {
            union { __bf16 b2[2]; unsigned v; } pk2;
            pk2.b2[0] = (__bf16)p[kb][2 * i];
            pk2.b2[1] = (__bf16)p[kb][2 * i + 1];
            u[i] = pk2.v;
          }
          asm("v_permlane32_swap_b32 %0, %1" : "+v"(u[0]), "+v"(u[2]));
          asm("v_permlane32_swap_b32 %0, %1" : "+v"(u[1]), "+v"(u[3]));
          asm("v_permlane32_swap_b32 %0, %1" : "+v"(u[4]), "+v"(u[6]));
          asm("v_permlane32_swap_b32 %0, %1" : "+v"(u[5]), "+v"(u[7]));
          union { unsigned u4[4]; bf16x8 v; } pf0, pf1;
          pf0.u4[0] = u[0]; pf0.u4[1] = u[1]; pf0.u4[2] = u[2]; pf0.u4[3] = u[3];
          pf1.u4[0] = u[4]; pf1.u4[1] = u[5]; pf1.u4[2] = u[6]; pf1.u4[3] = u[7];
          __builtin_amdgcn_s_setprio(1);
#pragma unroll
          for (int ks = 0; ks < 2; ks++) {
            const bf16x8 pf = ks ? pf1.v : pf0.v;
#pragma unroll
            for (int dt = 0; dt < 2; dt++) {
              bf16x8 vf = *(const bf16x8*)(vsb + (l & 31) * 128 + dt * 4096 +
                                           (((kb * 4 + ks * 2 + hi) ^ (l & 7)) << 4));
              oacc[dt] = __builtin_amdgcn_mfma_f32_32x32x16_bf16(vf, pf, oacc[dt], 0, 0, 0);
            }
          }
          __builtin_amdgcn_s_setprio(0);
        }
      }
    }

    // ---- epilogue: O^T regs -> att (bf16) for this strip ----
    const float inv = 1.0f / lsum;
    ushort_t* ob = att + (size_t)b * N_ * QD + (size_t)(wq0 + lq) * QD + h * D_;
#pragma unroll
    for (int dt = 0; dt < 2; dt++)
#pragma unroll
      for (int rq = 0; rq < 4; rq++) {
        union { ushort_t s4[4]; unsigned long long v; } o;
#pragma unroll
        for (int e = 0; e < 4; e++) o.s4[e] = bfbits(oacc[dt][rq * 4 + e] * inv);
        *(unsigned long long*)(ob + dt * 32 + 8 * rq + 4 * hi) = o.v;
      }
  }
}

extern "C" void kernel_launch(void* const* d_in, const int* in_sizes, int n_in,
                              void* d_out, int out_size, void* d_ws, size_t ws_size,
                              hipStream_t stream) {
  const float* x = (const float*)d_in[0];
  const float* ctx = (const float*)d_in[1];
  const float* Wq = (const float*)d_in[2];
  const float* Wk = (const float*)d_in[3];
  const float* Wv = (const float*)d_in[4];
  const float* Wo = (const float*)d_in[5];
  const float* bo = (const float*)d_in[6];
  float* out = (float*)d_out;

  char* ws = (char*)d_ws;
  size_t off = 0;
  ushort_t* xb = (ushort_t*)(ws + off);   off += (size_t)8192 * 1024 * 2;  // reused as qT
  ushort_t* qb = (ushort_t*)(ws + off);   off += (size_t)8192 * 1024 * 2;
  ushort_t* attb = (ushort_t*)(ws + off); off += (size_t)8192 * 1024 * 2;
  ushort_t* WqT = (ushort_t*)(ws + off);  off += (size_t)1024 * 1024 * 2;
  ushort_t* WoT = (ushort_t*)(ws + off);  off += (size_t)1024 * 1024 * 2;
  float* kctx = (float*)(ws + off);       off += (size_t)4096 * 4;
  float* vctx = (float*)(ws + off);       off += (size_t)4096 * 4;
  float* part = (float*)(ws + off);       off += (size_t)16 * 4096 * 4;
  ushort_t* qT = xb;  // xb is dead after k_gemm<1>

  k_cvt_bf16<<<dim3(4096), dim3(256), 0, stream>>>(x, xb, 8192 * 1024 / 8);
  k_transpose_w<<<dim3(16, 16, 2), dim3(256), 0, stream>>>(Wq, Wo, WqT, WoT);
  k_ctx_partial<<<dim3(4, 8, 2), dim3(256), 0, stream>>>(ctx, Wk, Wv, part);
  k_ctx_reduce<<<dim3(32), dim3(256), 0, stream>>>(part, kctx, vctx);
  k_gemm<1><<<dim3(8, 64), dim3(256), 0, stream>>>(xb, WqT, qb, nullptr, nullptr);
  k_transpose_q<<<dim3(32, 64), dim3(256), 0, stream>>>(qb, qT);
  k_attn8<<<dim3(512), dim3(256), 0, stream>>>(qb, qT, kctx, vctx, attb);
  k_gemm<0><<<dim3(8, 64), dim3(256), 0, stream>>>(attb, WoT, nullptr, out, bo);
}